// Round 6
// baseline (918.764 us; speedup 1.0000x reference)
//
#include <hip/hip_runtime.h>
#include <math.h>

#define R    116
#define R2   (116*116)
#define G    128
#define NN   (R*G)      // 14848 nodes
#define HID  64
#define EDIM 5
#define INCH 116
#define EMBD 16

__device__ __forceinline__ float waveReduceSum(float v) {
#pragma unroll
    for (int m = 32; m >= 1; m >>= 1) v += __shfl_xor(v, m, 64);
    return v;
}

// ---------------- edge-attr transpose: eat[g][j][i][e] = ea[g][i][j][e] -------
__global__ __launch_bounds__(256) void k_etr(
    const float* __restrict__ ea, float* __restrict__ eat) {
    int b = blockIdx.x;
    int g = b >> 4;
    int t = b & 15;
    int i0 = (t >> 2) << 5, j0 = (t & 3) << 5;
    int ni = min(32, R - i0), nj = min(32, R - j0);
    __shared__ float tile[32][165];
    const float* src = ea + ((size_t)(g*R + i0)*R + j0)*EDIM;
    int tot = ni * nj * EDIM;
    for (int idx = threadIdx.x; idx < tot; idx += 256) {
        int ii = idx / (nj*EDIM);
        int rem = idx - ii*(nj*EDIM);
        tile[ii][rem] = src[(size_t)ii*R*EDIM + rem];
    }
    __syncthreads();
    float* dst = eat + ((size_t)(g*R + j0)*R + i0)*EDIM;
    int tot2 = nj * ni * EDIM;
    for (int idx = threadIdx.x; idx < tot2; idx += 256) {
        int jj = idx / (ni*EDIM);
        int rem = idx - jj*(ni*EDIM);     // ii*5 + e
        int ii = rem / EDIM, e = rem - ii*EDIM;
        dst[(size_t)jj*R*EDIM + rem] = tile[ii][jj*EDIM + e];
    }
}

// ---------------- encode: h = relu([x, emb[gid]] @ W + b), 4 nodes/block ------
__global__ __launch_bounds__(256) void k_encode(
    const float* __restrict__ x, const float* __restrict__ emb,
    const int* __restrict__ group_ids,
    const float* __restrict__ W, const float* __restrict__ bvec,
    float* __restrict__ h) {
    int w = threadIdx.x >> 6, lane = threadIdx.x & 63;
    int n = blockIdx.x*4 + w;
    __shared__ float xin[4][136];
    for (int idx = lane; idx < INCH; idx += 64) xin[w][idx] = x[(size_t)n*INCH + idx];
    if (lane < EMBD) xin[w][INCH + lane] = emb[group_ids[n]*EMBD + lane];
    float acc = bvec[lane];
#pragma unroll
    for (int k = 0; k < INCH + EMBD; k += 4) {
        float4 q = *(const float4*)&xin[w][k];
        acc = fmaf(q.x, W[(k  )*HID + lane], acc);
        acc = fmaf(q.y, W[(k+1)*HID + lane], acc);
        acc = fmaf(q.z, W[(k+2)*HID + lane], acc);
        acc = fmaf(q.w, W[(k+3)*HID + lane], acc);
    }
    h[(size_t)n*HID + lane] = fmaxf(acc, 0.f);
}

// ---------------- batchnorm stats (two-stage, deterministic) ----------------
__global__ __launch_bounds__(256) void k_stats_partial(
    const float* __restrict__ h, float* __restrict__ partials) {
    int b = blockIdx.x;
    int tid = threadIdx.x;
    int c = tid & 63, r0 = tid >> 6;
    float s = 0.f, s2 = 0.f;
    int row0 = b*64;
#pragma unroll
    for (int k = 0; k < 16; ++k) {
        float v = h[(size_t)(row0 + r0 + 4*k)*HID + c];
        s += v; s2 += v*v;
    }
    __shared__ float ls[256], l2[256];
    ls[tid] = s; l2[tid] = s2;
    __syncthreads();
    if (tid < 64) {
        s  = ls[tid] + ls[tid+64] + ls[tid+128] + ls[tid+192];
        s2 = l2[tid] + l2[tid+64] + l2[tid+128] + l2[tid+192];
        partials[b*128 + tid]      = s;
        partials[b*128 + 64 + tid] = s2;
    }
}

__global__ __launch_bounds__(64) void k_stats_final(
    const float* __restrict__ partials, const float* __restrict__ gam,
    const float* __restrict__ bet, float* __restrict__ stats) {
    int c = threadIdx.x;
    float s = 0.f, s2 = 0.f;
    for (int b = 0; b < NN/64; ++b) {
        s  += partials[b*128 + c];
        s2 += partials[b*128 + 64 + c];
    }
    float mu  = s / (float)NN;
    float var = s2 / (float)NN - mu*mu;
    float rs  = rsqrtf(var + 1e-5f);
    float sc  = rs * gam[c];
    stats[c]      = sc;
    stats[64 + c] = bet[c] - mu*sc;
}

// ------- GINE: BN fused on load, 4 dsts/wave jointly, uniform edge loads -----
__global__ __launch_bounds__(256, 4) void k_gine(
    const float* __restrict__ h, const float* __restrict__ stats,
    const float* __restrict__ eat,
    const float* __restrict__ We, const float* __restrict__ be,
    const float* __restrict__ W1, const float* __restrict__ b1,
    const float* __restrict__ W2, const float* __restrict__ b2,
    float* __restrict__ hout) {
    int b = blockIdx.x;
    int g = b & (G-1), chunk = b >> 7;     // 8 chunks x 15 dsts
    int j0 = chunk*15;
    int tid = threadIdx.x, w = tid >> 6, lane = tid & 63;
    __shared__ float hs[R][64];
    __shared__ float t1s[4][68];
    size_t hbase = (size_t)g*R*HID;
    float scv = stats[lane], shv = stats[64 + lane];
    for (int idx = tid; idx < R*HID; idx += 256)
        hs[idx>>6][lane] = fmaf(h[hbase + idx], scv, shv);
    float w0=We[lane], w1v=We[64+lane], w2v=We[128+lane],
          w3v=We[192+lane], w4v=We[256+lane], bec=be[lane];
    __syncthreads();

    bool act[4]; int jv[4];
    const float* cp[4];
#pragma unroll
    for (int t = 0; t < 4; ++t) {
        int jj = w + 4*t;
        int j = j0 + jj;
        act[t] = (jj < 15) && (j < R);
        jv[t] = act[t] ? j : (R-1);
        cp[t] = eat + (size_t)(g*R + jv[t])*R*EDIM;
    }
    float agg0 = 0.f, agg1 = 0.f, agg2 = 0.f, agg3 = 0.f;
    for (int i = 0; i < R; ++i) {
        float hv = hs[i][lane];
        float4 q0, q1, q2, q3;
        __builtin_memcpy(&q0, cp[0] + i*EDIM, 16); float q04 = cp[0][i*EDIM+4];
        __builtin_memcpy(&q1, cp[1] + i*EDIM, 16); float q14 = cp[1][i*EDIM+4];
        __builtin_memcpy(&q2, cp[2] + i*EDIM, 16); float q24 = cp[2][i*EDIM+4];
        __builtin_memcpy(&q3, cp[3] + i*EDIM, 16); float q34 = cp[3][i*EDIM+4];
        float e0 = bec, e1 = bec, e2 = bec, e3 = bec;
        e0 = fmaf(q0.x,w0,e0); e0 = fmaf(q0.y,w1v,e0); e0 = fmaf(q0.z,w2v,e0);
        e0 = fmaf(q0.w,w3v,e0); e0 = fmaf(q04,w4v,e0);
        e1 = fmaf(q1.x,w0,e1); e1 = fmaf(q1.y,w1v,e1); e1 = fmaf(q1.z,w2v,e1);
        e1 = fmaf(q1.w,w3v,e1); e1 = fmaf(q14,w4v,e1);
        e2 = fmaf(q2.x,w0,e2); e2 = fmaf(q2.y,w1v,e2); e2 = fmaf(q2.z,w2v,e2);
        e2 = fmaf(q2.w,w3v,e2); e2 = fmaf(q24,w4v,e2);
        e3 = fmaf(q3.x,w0,e3); e3 = fmaf(q3.y,w1v,e3); e3 = fmaf(q3.z,w2v,e3);
        e3 = fmaf(q3.w,w3v,e3); e3 = fmaf(q34,w4v,e3);
        agg0 += fmaxf(hv + e0, 0.f);
        agg1 += fmaxf(hv + e1, 0.f);
        agg2 += fmaxf(hv + e2, 0.f);
        agg3 += fmaxf(hv + e3, 0.f);
    }
    float aggs[4] = {agg0, agg1, agg2, agg3};
#pragma unroll
    for (int t = 0; t < 4; ++t) {
        if (!act[t]) continue;             // wave-uniform branch
        float h1 = hs[jv[t]][lane] + aggs[t];
        t1s[w][lane] = h1;                 // same-wave in-order LDS
        float acc = b1[lane];
#pragma unroll
        for (int k = 0; k < HID; k += 4) {
            float4 tq = *(const float4*)&t1s[w][k];
            acc = fmaf(tq.x, W1[(k  )*HID + lane], acc);
            acc = fmaf(tq.y, W1[(k+1)*HID + lane], acc);
            acc = fmaf(tq.z, W1[(k+2)*HID + lane], acc);
            acc = fmaf(tq.w, W1[(k+3)*HID + lane], acc);
        }
        t1s[w][lane] = fmaxf(acc, 0.f);
        float acc2 = b2[lane];
#pragma unroll
        for (int k = 0; k < HID; k += 4) {
            float4 tq = *(const float4*)&t1s[w][k];
            acc2 = fmaf(tq.x, W2[(k  )*HID + lane], acc2);
            acc2 = fmaf(tq.y, W2[(k+1)*HID + lane], acc2);
            acc2 = fmaf(tq.z, W2[(k+2)*HID + lane], acc2);
            acc2 = fmaf(tq.w, W2[(k+3)*HID + lane], acc2);
        }
        hout[hbase + (size_t)jv[t]*HID + lane] = fmaxf(acc2, 0.f);
    }
}

// ---------------- GAT: xl/xr projections + att-dot precompute ----------------
__global__ __launch_bounds__(256) void k_xlxr(
    const float* __restrict__ h,
    const float* __restrict__ Wl, const float* __restrict__ bl,
    const float* __restrict__ Wr, const float* __restrict__ br,
    const float* __restrict__ att,
    float* __restrict__ xl, float* __restrict__ xr,
    float* __restrict__ axl, float* __restrict__ axr) {
    int w = threadIdx.x >> 6, lane = threadIdx.x & 63;
    int n = blockIdx.x*4 + w;
    __shared__ float hr[4][68];
    hr[w][lane] = h[(size_t)n*HID + lane];
    float aL = bl[lane], aR = br[lane];
#pragma unroll
    for (int k = 0; k < HID; k += 4) {
        float4 q = *(const float4*)&hr[w][k];
        aL = fmaf(q.x, Wl[(k  )*HID + lane], aL);
        aR = fmaf(q.x, Wr[(k  )*HID + lane], aR);
        aL = fmaf(q.y, Wl[(k+1)*HID + lane], aL);
        aR = fmaf(q.y, Wr[(k+1)*HID + lane], aR);
        aL = fmaf(q.z, Wl[(k+2)*HID + lane], aL);
        aR = fmaf(q.z, Wr[(k+2)*HID + lane], aR);
        aL = fmaf(q.w, Wl[(k+3)*HID + lane], aL);
        aR = fmaf(q.w, Wr[(k+3)*HID + lane], aR);
    }
    xl[(size_t)n*HID + lane] = aL;
    xr[(size_t)n*HID + lane] = aR;
    float at = att[lane];
    float pL = waveReduceSum(aL * at);
    float pR = waveReduceSum(aR * at);
    if (lane == 0) { axl[n] = pL; axr[n] = pR; }
}

// ------- GAT: 4 dsts/wave jointly, abs-decomposed score, paired agg ----------
__global__ __launch_bounds__(256, 4) void k_gat(
    const float* __restrict__ xl, const float* __restrict__ xr,
    const float* __restrict__ axlg, const float* __restrict__ axrg,
    const float* __restrict__ eat, const float* __restrict__ We,
    const float* __restrict__ att, const float* __restrict__ bias,
    float* __restrict__ hout) {
    int b = blockIdx.x;
    int g = b & (G-1), chunk = b >> 7;     // 8 chunks x 15 dsts
    int j0 = chunk*15;
    int tid = threadIdx.x, w = tid >> 6, lane = tid & 63;
    __shared__ float xls[R][65];
    __shared__ float we_s[64][8];          // {We0..4, att, pad, pad}
    __shared__ float ps[4][2][120];
    __shared__ float was_s[8];             // We @ att
    size_t hbase = (size_t)g*R*HID;
    for (int idx = tid; idx < R*HID; idx += 256)
        xls[idx>>6][idx&63] = xl[hbase + idx];
    if (w == 1) {
        float g0=We[lane], g1=We[64+lane], g2=We[128+lane],
              g3=We[192+lane], g4=We[256+lane], at=att[lane];
        we_s[lane][0]=g0; we_s[lane][1]=g1; we_s[lane][2]=g2;
        we_s[lane][3]=g3; we_s[lane][4]=g4; we_s[lane][5]=at;
        we_s[lane][6]=0.f; we_s[lane][7]=0.f;
        float p0 = waveReduceSum(g0*at);
        float p1 = waveReduceSum(g1*at);
        float p2 = waveReduceSum(g2*at);
        float p3 = waveReduceSum(g3*at);
        float p4 = waveReduceSum(g4*at);
        if (lane == 0) { was_s[0]=p0; was_s[1]=p1; was_s[2]=p2;
                         was_s[3]=p3; was_s[4]=p4; }
    }
    __syncthreads();
    float wasv0=was_s[0], wasv1=was_s[1], wasv2=was_s[2],
          wasv3=was_s[3], wasv4=was_s[4];
    float biasv = bias[lane];
    bool vB = lane < (R - 64);
    int rb = vB ? (64 + lane) : lane;      // clamped B-row
    float axA = axlg[g*R + lane];
    float axB = axlg[g*R + rb];

    bool act[4]; int jv[4];
    float axr_[4];
    float eA[4][5], eB[4][5];
#pragma unroll
    for (int t = 0; t < 4; ++t) {
        int jj = w + 4*t;
        int j = j0 + jj;
        act[t] = (jj < 15) && (j < R);
        jv[t] = act[t] ? j : (R-1);
        axr_[t] = axrg[g*R + jv[t]];
        const float* cp = eat + (size_t)(g*R + jv[t])*R*EDIM;
#pragma unroll
        for (int e = 0; e < 5; ++e) eA[t][e] = cp[lane*EDIM + e];
#pragma unroll
        for (int e = 0; e < 5; ++e) eB[t][e] = cp[rb*EDIM + e];
    }
    const float* xrg = xr + hbase;
    float accA[4] = {0,0,0,0}, accB[4] = {0,0,0,0};
#pragma unroll 4
    for (int c = 0; c < HID; ++c) {
        float4 qa = *(const float4*)&we_s[c][0];
        float2 qb = *(const float2*)&we_s[c][4];   // {We4, att}
        float xA = xls[lane][c];
        float xB = xls[rb][c];
#pragma unroll
        for (int t = 0; t < 4; ++t) {
            float u = xrg[(size_t)jv[t]*HID + c];  // uniform global, L1/L2-hot
            float zA = xA + u;
            zA = fmaf(eA[t][0],qa.x,zA); zA = fmaf(eA[t][1],qa.y,zA);
            zA = fmaf(eA[t][2],qa.z,zA); zA = fmaf(eA[t][3],qa.w,zA);
            zA = fmaf(eA[t][4],qb.x,zA);
            accA[t] = fmaf(__builtin_fabsf(zA), qb.y, accA[t]);
            float zB = xB + u;
            zB = fmaf(eB[t][0],qa.x,zB); zB = fmaf(eB[t][1],qa.y,zB);
            zB = fmaf(eB[t][2],qa.z,zB); zB = fmaf(eB[t][3],qa.w,zB);
            zB = fmaf(eB[t][4],qb.x,zB);
            accB[t] = fmaf(__builtin_fabsf(zB), qb.y, accB[t]);
        }
    }
    float o[4];
#pragma unroll
    for (int t = 0; t < 4; ++t) {
        float LA = axA + axr_[t], LB = axB + axr_[t];
        LA = fmaf(eA[t][0],wasv0,LA); LA = fmaf(eA[t][1],wasv1,LA);
        LA = fmaf(eA[t][2],wasv2,LA); LA = fmaf(eA[t][3],wasv3,LA);
        LA = fmaf(eA[t][4],wasv4,LA);
        LB = fmaf(eB[t][0],wasv0,LB); LB = fmaf(eB[t][1],wasv1,LB);
        LB = fmaf(eB[t][2],wasv2,LB); LB = fmaf(eB[t][3],wasv3,LB);
        LB = fmaf(eB[t][4],wasv4,LB);
        // lrelu(z,0.2) = 0.6z + 0.4|z|  =>  score = 0.6*L + 0.4*acc
        float sA = fmaf(0.4f, accA[t], 0.6f*LA);
        float sB = vB ? fmaf(0.4f, accB[t], 0.6f*LB) : -1e30f;
        float m = fmaxf(sA, sB);
#pragma unroll
        for (int msk = 32; msk >= 1; msk >>= 1) m = fmaxf(m, __shfl_xor(m, msk, 64));
        float eAx = __expf(sA - m);
        float eBx = vB ? __expf(sB - m) : 0.f;
        float s = eAx + eBx;
#pragma unroll
        for (int msk = 32; msk >= 1; msk >>= 1) s += __shfl_xor(s, msk, 64);
        float inv = 1.f / (s + 1e-16f);
        ps[w][t&1][lane] = eAx * inv;
        if (vB) ps[w][t&1][64 + lane] = eBx * inv;
        if (t & 1) {                       // paired aggregation (same-wave LDS)
            float o0 = 0.f, o1 = 0.f;
            for (int i = 0; i < R; i += 4) {
                float4 p0 = *(const float4*)&ps[w][0][i];
                float4 p1 = *(const float4*)&ps[w][1][i];
                float x0 = xls[i  ][lane], x1 = xls[i+1][lane];
                float x2 = xls[i+2][lane], x3 = xls[i+3][lane];
                o0 = fmaf(p0.x,x0,o0); o0 = fmaf(p0.y,x1,o0);
                o0 = fmaf(p0.z,x2,o0); o0 = fmaf(p0.w,x3,o0);
                o1 = fmaf(p1.x,x0,o1); o1 = fmaf(p1.y,x1,o1);
                o1 = fmaf(p1.z,x2,o1); o1 = fmaf(p1.w,x3,o1);
            }
            o[t-1] = o0; o[t] = o1;
        }
    }
#pragma unroll
    for (int t = 0; t < 4; ++t)
        if (act[t])
            hout[hbase + (size_t)jv[t]*HID + lane] = fmaxf(o[t] + biasv, 0.f);
}

// ---------------- pooling ----------------
__global__ __launch_bounds__(256) void k_pool_score(
    const float* __restrict__ h, const float* __restrict__ W1,
    const float* __restrict__ b1, const float* __restrict__ w2,
    float* __restrict__ scores) {
    int w = threadIdx.x >> 6, lane = threadIdx.x & 63;
    int n = blockIdx.x*4 + w;
    __shared__ float hr[4][68];
    hr[w][lane] = h[(size_t)n*HID + lane];
    float acc = b1[lane];
#pragma unroll
    for (int k = 0; k < HID; k += 4) {
        float4 q = *(const float4*)&hr[w][k];
        acc = fmaf(q.x, W1[(k  )*HID + lane], acc);
        acc = fmaf(q.y, W1[(k+1)*HID + lane], acc);
        acc = fmaf(q.z, W1[(k+2)*HID + lane], acc);
        acc = fmaf(q.w, W1[(k+3)*HID + lane], acc);
    }
    float p = tanhf(acc) * w2[lane];
    p = waveReduceSum(p);
    if (lane == 0) scores[n] = p;
}

__global__ __launch_bounds__(1024) void k_pool_reduce(
    const float* __restrict__ scores, float* __restrict__ ms) {
    __shared__ float red[1024];
    int tid = threadIdx.x;
    float m = -1e30f;
    for (int i = tid; i < NN; i += 1024) m = fmaxf(m, scores[i]);
    red[tid] = m;
    __syncthreads();
    for (int s = 512; s > 0; s >>= 1) {
        if (tid < s) red[tid] = fmaxf(red[tid], red[tid+s]);
        __syncthreads();
    }
    float mx = red[0];
    __syncthreads();
    float sum = 0.f;
    for (int i = tid; i < NN; i += 1024) sum += __expf(scores[i] - mx);
    red[tid] = sum;
    __syncthreads();
    for (int s = 512; s > 0; s >>= 1) {
        if (tid < s) red[tid] += red[tid+s];
        __syncthreads();
    }
    if (tid == 0) { ms[0] = mx; ms[1] = red[0]; }
}

__global__ __launch_bounds__(64) void k_pool_final(
    const float* __restrict__ h, const float* __restrict__ scores,
    const float* __restrict__ ms,
    const float* __restrict__ lin1W, const float* __restrict__ lin1b,
    const float* __restrict__ lin2W, const float* __restrict__ lin2b,
    float* __restrict__ out) {
    int g = blockIdx.x, c = threadIdx.x;
    float mx = ms[0], inv = 1.f / ms[1];
    float pc = 0.f;
    int nb = g*R;
    for (int r = 0; r < R; ++r) {
        float wv = __expf(scores[nb + r] - mx) * inv;
        pc = fmaf(h[(size_t)(nb + r)*HID + c], wv, pc);
    }
    __shared__ float pl[HID];
    __shared__ float t[INCH];
    pl[c] = pc;
    __syncthreads();
    for (int k = c; k < INCH; k += 64) {
        float acc = lin1b[k];
#pragma unroll 8
        for (int q = 0; q < HID; ++q) acc = fmaf(pl[q], lin1W[q*INCH + k], acc);
        t[k] = fmaxf(acc, 0.f);
    }
    __syncthreads();
    if (c < 2) {
        float o = lin2b[c];
        for (int k = 0; k < INCH; ++k) o = fmaf(t[k], lin2W[k*2 + c], o);
        out[g*2 + c] = o;
    }
}

extern "C" void kernel_launch(void* const* d_in, const int* in_sizes, int n_in,
                              void* d_out, int out_size, void* d_ws, size_t ws_size,
                              hipStream_t stream) {
    (void)in_sizes; (void)n_in; (void)out_size; (void)ws_size;
    const float* x        = (const float*)d_in[0];
    const float* edge_attr= (const float*)d_in[1];
    const float* emb      = (const float*)d_in[2];
    const float* enc_W    = (const float*)d_in[3];
    const float* enc_b    = (const float*)d_in[4];
    const float* bn_g     = (const float*)d_in[5];
    const float* bn_b     = (const float*)d_in[6];
    const float* gine_We  = (const float*)d_in[7];
    const float* gine_be  = (const float*)d_in[8];
    const float* gine_W1  = (const float*)d_in[9];
    const float* gine_b1  = (const float*)d_in[10];
    const float* gine_W2  = (const float*)d_in[11];
    const float* gine_b2  = (const float*)d_in[12];
    const float* gat_Wl   = (const float*)d_in[13];
    const float* gat_bl   = (const float*)d_in[14];
    const float* gat_Wr   = (const float*)d_in[15];
    const float* gat_br   = (const float*)d_in[16];
    const float* gat_att  = (const float*)d_in[17];
    const float* gat_We   = (const float*)d_in[18];
    const float* gat_bias = (const float*)d_in[19];
    const float* pool_W1  = (const float*)d_in[20];
    const float* pool_b1  = (const float*)d_in[21];
    const float* pool_w2  = (const float*)d_in[22];
    const float* lin1_W   = (const float*)d_in[23];
    const float* lin1_b   = (const float*)d_in[24];
    const float* lin2_W   = (const float*)d_in[25];
    const float* lin2_b   = (const float*)d_in[26];
    const int*   group_ids= (const int*)d_in[29];
    float* out = (float*)d_out;

    float* w = (float*)d_ws;
    float* eat      = w;                            // R2*G*EDIM
    float* hA       = eat + (size_t)R2*G*EDIM;      // NN*HID
    float* hB       = hA + (size_t)NN*HID;
    float* xlb      = hB + (size_t)NN*HID;
    float* xrb      = xlb + (size_t)NN*HID;
    float* axl      = xrb + (size_t)NN*HID;         // NN
    float* axr      = axl + NN;                     // NN
    float* scores   = axr + NN;                     // NN
    float* partials = scores + NN;                  // 232*128
    float* stats    = partials + (NN/64)*128;       // 128
    float* pms      = stats + 128;                  // 2

    k_etr<<<G*16, 256, 0, stream>>>(edge_attr, eat);
    k_encode<<<NN/4, 256, 0, stream>>>(x, emb, group_ids, enc_W, enc_b, hA);
    k_stats_partial<<<NN/64, 256, 0, stream>>>(hA, partials);
    k_stats_final<<<1, 64, 0, stream>>>(partials, bn_g, bn_b, stats);
    k_gine<<<G*8, 256, 0, stream>>>(hA, stats, eat, gine_We, gine_be,
                                    gine_W1, gine_b1, gine_W2, gine_b2, hB);
    // GAT layer 0: hB -> hA
    k_xlxr<<<NN/4, 256, 0, stream>>>(hB, gat_Wl, gat_bl, gat_Wr, gat_br,
                                     gat_att, xlb, xrb, axl, axr);
    k_gat<<<G*8, 256, 0, stream>>>(xlb, xrb, axl, axr, eat, gat_We,
                                   gat_att, gat_bias, hA);
    // GAT layer 1: hA -> hB
    k_xlxr<<<NN/4, 256, 0, stream>>>(hA, gat_Wl + HID*HID, gat_bl + HID,
                                     gat_Wr + HID*HID, gat_br + HID,
                                     gat_att + HID, xlb, xrb, axl, axr);
    k_gat<<<G*8, 256, 0, stream>>>(xlb, xrb, axl, axr, eat, gat_We + EDIM*HID,
                                   gat_att + HID, gat_bias + HID, hB);
    // pooling + head
    k_pool_score<<<NN/4, 256, 0, stream>>>(hB, pool_W1, pool_b1, pool_w2, scores);
    k_pool_reduce<<<1, 1024, 0, stream>>>(scores, pms);
    k_pool_final<<<G, 64, 0, stream>>>(hB, scores, pms, lin1_W, lin1_b,
                                       lin2_W, lin2_b, out);
}

// Round 7
// 353.066 us; speedup vs baseline: 2.6022x; 2.6022x over previous
//
#include <hip/hip_runtime.h>
#include <math.h>

#define R    116
#define R2   (116*116)
#define G    128
#define NN   (R*G)      // 14848 nodes
#define HID  64
#define EDIM 5
#define INCH 116
#define EMBD 16

__device__ __forceinline__ float waveReduceSum(float v) {
#pragma unroll
    for (int m = 32; m >= 1; m >>= 1) v += __shfl_xor(v, m, 64);
    return v;
}

// ---------------- edge-attr transpose: eat[g][j][i][e] = ea[g][i][j][e] -------
__global__ __launch_bounds__(256) void k_etr(
    const float* __restrict__ ea, float* __restrict__ eat) {
    int b = blockIdx.x;
    int g = b >> 4;
    int t = b & 15;
    int i0 = (t >> 2) << 5, j0 = (t & 3) << 5;
    int ni = min(32, R - i0), nj = min(32, R - j0);
    __shared__ float tile[32][165];
    const float* src = ea + ((size_t)(g*R + i0)*R + j0)*EDIM;
    int tot = ni * nj * EDIM;
    for (int idx = threadIdx.x; idx < tot; idx += 256) {
        int ii = idx / (nj*EDIM);
        int rem = idx - ii*(nj*EDIM);
        tile[ii][rem] = src[(size_t)ii*R*EDIM + rem];
    }
    __syncthreads();
    float* dst = eat + ((size_t)(g*R + j0)*R + i0)*EDIM;
    int tot2 = nj * ni * EDIM;
    for (int idx = threadIdx.x; idx < tot2; idx += 256) {
        int jj = idx / (ni*EDIM);
        int rem = idx - jj*(ni*EDIM);     // ii*5 + e
        int ii = rem / EDIM, e = rem - ii*EDIM;
        dst[(size_t)jj*R*EDIM + rem] = tile[ii][jj*EDIM + e];
    }
}

// ---------------- encode: h = relu([x, emb[gid]] @ W + b), 4 nodes/block ------
__global__ __launch_bounds__(256) void k_encode(
    const float* __restrict__ x, const float* __restrict__ emb,
    const int* __restrict__ group_ids,
    const float* __restrict__ W, const float* __restrict__ bvec,
    float* __restrict__ h) {
    int w = threadIdx.x >> 6, lane = threadIdx.x & 63;
    int n = blockIdx.x*4 + w;
    __shared__ float xin[4][136];
    for (int idx = lane; idx < INCH; idx += 64) xin[w][idx] = x[(size_t)n*INCH + idx];
    if (lane < EMBD) xin[w][INCH + lane] = emb[group_ids[n]*EMBD + lane];
    float acc = bvec[lane];
#pragma unroll
    for (int k = 0; k < INCH + EMBD; k += 4) {
        float4 q = *(const float4*)&xin[w][k];
        acc = fmaf(q.x, W[(k  )*HID + lane], acc);
        acc = fmaf(q.y, W[(k+1)*HID + lane], acc);
        acc = fmaf(q.z, W[(k+2)*HID + lane], acc);
        acc = fmaf(q.w, W[(k+3)*HID + lane], acc);
    }
    h[(size_t)n*HID + lane] = fmaxf(acc, 0.f);
}

// ---------------- batchnorm stats (two-stage, deterministic) ----------------
__global__ __launch_bounds__(256) void k_stats_partial(
    const float* __restrict__ h, float* __restrict__ partials) {
    int b = blockIdx.x;
    int tid = threadIdx.x;
    int c = tid & 63, r0 = tid >> 6;
    float s = 0.f, s2 = 0.f;
    int row0 = b*64;
#pragma unroll
    for (int k = 0; k < 16; ++k) {
        float v = h[(size_t)(row0 + r0 + 4*k)*HID + c];
        s += v; s2 += v*v;
    }
    __shared__ float ls[256], l2[256];
    ls[tid] = s; l2[tid] = s2;
    __syncthreads();
    if (tid < 64) {
        s  = ls[tid] + ls[tid+64] + ls[tid+128] + ls[tid+192];
        s2 = l2[tid] + l2[tid+64] + l2[tid+128] + l2[tid+192];
        partials[b*128 + tid]      = s;
        partials[b*128 + 64 + tid] = s2;
    }
}

__global__ __launch_bounds__(64) void k_stats_final(
    const float* __restrict__ partials, const float* __restrict__ gam,
    const float* __restrict__ bet, float* __restrict__ stats) {
    int c = threadIdx.x;
    float s = 0.f, s2 = 0.f;
    for (int b = 0; b < NN/64; ++b) {
        s  += partials[b*128 + c];
        s2 += partials[b*128 + 64 + c];
    }
    float mu  = s / (float)NN;
    float var = s2 / (float)NN - mu*mu;
    float rs  = rsqrtf(var + 1e-5f);
    float sc  = rs * gam[c];
    stats[c]      = sc;
    stats[64 + c] = bet[c] - mu*sc;
}

// ------- GINE: BN fused on load, 4 dsts/wave jointly, uniform edge loads -----
__global__ __launch_bounds__(256) void k_gine(
    const float* __restrict__ h, const float* __restrict__ stats,
    const float* __restrict__ eat,
    const float* __restrict__ We, const float* __restrict__ be,
    const float* __restrict__ W1, const float* __restrict__ b1,
    const float* __restrict__ W2, const float* __restrict__ b2,
    float* __restrict__ hout) {
    int b = blockIdx.x;
    int g = b & (G-1), chunk = b >> 7;     // 8 chunks x 15 dsts
    int j0 = chunk*15;
    int tid = threadIdx.x, w = tid >> 6, lane = tid & 63;
    __shared__ float hs[R][64];
    __shared__ float t1s[4][68];
    size_t hbase = (size_t)g*R*HID;
    float scv = stats[lane], shv = stats[64 + lane];
    for (int idx = tid; idx < R*HID; idx += 256)
        hs[idx>>6][lane] = fmaf(h[hbase + idx], scv, shv);
    float w0=We[lane], w1v=We[64+lane], w2v=We[128+lane],
          w3v=We[192+lane], w4v=We[256+lane], bec=be[lane];
    __syncthreads();

    bool act[4]; int jv[4];
    const float* cp[4];
#pragma unroll
    for (int t = 0; t < 4; ++t) {
        int jj = w + 4*t;
        int j = j0 + jj;
        act[t] = (jj < 15) && (j < R);
        jv[t] = act[t] ? j : (R-1);
        cp[t] = eat + (size_t)(g*R + jv[t])*R*EDIM;
    }
    float agg0 = 0.f, agg1 = 0.f, agg2 = 0.f, agg3 = 0.f;
    for (int i = 0; i < R; ++i) {
        float hv = hs[i][lane];
        float4 q0, q1, q2, q3;
        __builtin_memcpy(&q0, cp[0] + i*EDIM, 16); float q04 = cp[0][i*EDIM+4];
        __builtin_memcpy(&q1, cp[1] + i*EDIM, 16); float q14 = cp[1][i*EDIM+4];
        __builtin_memcpy(&q2, cp[2] + i*EDIM, 16); float q24 = cp[2][i*EDIM+4];
        __builtin_memcpy(&q3, cp[3] + i*EDIM, 16); float q34 = cp[3][i*EDIM+4];
        float e0 = bec, e1 = bec, e2 = bec, e3 = bec;
        e0 = fmaf(q0.x,w0,e0); e0 = fmaf(q0.y,w1v,e0); e0 = fmaf(q0.z,w2v,e0);
        e0 = fmaf(q0.w,w3v,e0); e0 = fmaf(q04,w4v,e0);
        e1 = fmaf(q1.x,w0,e1); e1 = fmaf(q1.y,w1v,e1); e1 = fmaf(q1.z,w2v,e1);
        e1 = fmaf(q1.w,w3v,e1); e1 = fmaf(q14,w4v,e1);
        e2 = fmaf(q2.x,w0,e2); e2 = fmaf(q2.y,w1v,e2); e2 = fmaf(q2.z,w2v,e2);
        e2 = fmaf(q2.w,w3v,e2); e2 = fmaf(q24,w4v,e2);
        e3 = fmaf(q3.x,w0,e3); e3 = fmaf(q3.y,w1v,e3); e3 = fmaf(q3.z,w2v,e3);
        e3 = fmaf(q3.w,w3v,e3); e3 = fmaf(q34,w4v,e3);
        agg0 += fmaxf(hv + e0, 0.f);
        agg1 += fmaxf(hv + e1, 0.f);
        agg2 += fmaxf(hv + e2, 0.f);
        agg3 += fmaxf(hv + e3, 0.f);
    }
    float aggs[4] = {agg0, agg1, agg2, agg3};
#pragma unroll
    for (int t = 0; t < 4; ++t) {
        if (!act[t]) continue;             // wave-uniform branch
        float h1 = hs[jv[t]][lane] + aggs[t];
        t1s[w][lane] = h1;                 // same-wave in-order LDS
        float acc = b1[lane];
#pragma unroll
        for (int k = 0; k < HID; k += 4) {
            float4 tq = *(const float4*)&t1s[w][k];
            acc = fmaf(tq.x, W1[(k  )*HID + lane], acc);
            acc = fmaf(tq.y, W1[(k+1)*HID + lane], acc);
            acc = fmaf(tq.z, W1[(k+2)*HID + lane], acc);
            acc = fmaf(tq.w, W1[(k+3)*HID + lane], acc);
        }
        t1s[w][lane] = fmaxf(acc, 0.f);
        float acc2 = b2[lane];
#pragma unroll
        for (int k = 0; k < HID; k += 4) {
            float4 tq = *(const float4*)&t1s[w][k];
            acc2 = fmaf(tq.x, W2[(k  )*HID + lane], acc2);
            acc2 = fmaf(tq.y, W2[(k+1)*HID + lane], acc2);
            acc2 = fmaf(tq.z, W2[(k+2)*HID + lane], acc2);
            acc2 = fmaf(tq.w, W2[(k+3)*HID + lane], acc2);
        }
        hout[hbase + (size_t)jv[t]*HID + lane] = fmaxf(acc2, 0.f);
    }
}

// ---------------- GAT: xl/xr projections + att-dot precompute ----------------
__global__ __launch_bounds__(256) void k_xlxr(
    const float* __restrict__ h,
    const float* __restrict__ Wl, const float* __restrict__ bl,
    const float* __restrict__ Wr, const float* __restrict__ br,
    const float* __restrict__ att,
    float* __restrict__ xl, float* __restrict__ xr,
    float* __restrict__ axl, float* __restrict__ axr) {
    int w = threadIdx.x >> 6, lane = threadIdx.x & 63;
    int n = blockIdx.x*4 + w;
    __shared__ float hr[4][68];
    hr[w][lane] = h[(size_t)n*HID + lane];
    float aL = bl[lane], aR = br[lane];
#pragma unroll
    for (int k = 0; k < HID; k += 4) {
        float4 q = *(const float4*)&hr[w][k];
        aL = fmaf(q.x, Wl[(k  )*HID + lane], aL);
        aR = fmaf(q.x, Wr[(k  )*HID + lane], aR);
        aL = fmaf(q.y, Wl[(k+1)*HID + lane], aL);
        aR = fmaf(q.y, Wr[(k+1)*HID + lane], aR);
        aL = fmaf(q.z, Wl[(k+2)*HID + lane], aL);
        aR = fmaf(q.z, Wr[(k+2)*HID + lane], aR);
        aL = fmaf(q.w, Wl[(k+3)*HID + lane], aL);
        aR = fmaf(q.w, Wr[(k+3)*HID + lane], aR);
    }
    xl[(size_t)n*HID + lane] = aL;
    xr[(size_t)n*HID + lane] = aR;
    float at = att[lane];
    float pL = waveReduceSum(aL * at);
    float pR = waveReduceSum(aR * at);
    if (lane == 0) { axl[n] = pL; axr[n] = pR; }
}

// ------- GAT: 2 dsts/wave jointly (x2 pairs), abs-decomposed score -----------
__global__ __launch_bounds__(256) void k_gat(
    const float* __restrict__ xl, const float* __restrict__ xr,
    const float* __restrict__ axlg, const float* __restrict__ axrg,
    const float* __restrict__ eat, const float* __restrict__ We,
    const float* __restrict__ att, const float* __restrict__ bias,
    float* __restrict__ hout) {
    int b = blockIdx.x;
    int g = b & (G-1), chunk = b >> 7;     // 8 chunks x 15 dsts
    int j0 = chunk*15, jcnt = min(15, R - j0);
    int tid = threadIdx.x, w = tid >> 6, lane = tid & 63;
    __shared__ float xls[R][65];
    __shared__ float we_s[64][8];          // {We0..4, att, pad, pad}
    __shared__ float xrs[16][64];
    __shared__ float ps[4][2][120];
    __shared__ float was_s[8];             // We @ att
    size_t hbase = (size_t)g*R*HID;
    for (int idx = tid; idx < R*HID; idx += 256)
        xls[idx>>6][idx&63] = xl[hbase + idx];
    for (int idx = tid; idx < jcnt*HID; idx += 256)
        xrs[idx>>6][idx&63] = xr[hbase + (size_t)j0*HID + idx];
    if (w == 1) {
        float g0=We[lane], g1=We[64+lane], g2=We[128+lane],
              g3=We[192+lane], g4=We[256+lane], at=att[lane];
        we_s[lane][0]=g0; we_s[lane][1]=g1; we_s[lane][2]=g2;
        we_s[lane][3]=g3; we_s[lane][4]=g4; we_s[lane][5]=at;
        we_s[lane][6]=0.f; we_s[lane][7]=0.f;
        float p0 = waveReduceSum(g0*at);
        float p1 = waveReduceSum(g1*at);
        float p2 = waveReduceSum(g2*at);
        float p3 = waveReduceSum(g3*at);
        float p4 = waveReduceSum(g4*at);
        if (lane == 0) { was_s[0]=p0; was_s[1]=p1; was_s[2]=p2;
                         was_s[3]=p3; was_s[4]=p4; }
    }
    __syncthreads();
    float wasv0=was_s[0], wasv1=was_s[1], wasv2=was_s[2],
          wasv3=was_s[3], wasv4=was_s[4];
    float biasv = bias[lane];
    bool vB = lane < (R - 64);
    int rb = vB ? (64 + lane) : lane;      // clamped B-row
    float axA = axlg[g*R + lane];
    float axB = axlg[g*R + rb];

    for (int p = 0; p < 2; ++p) {          // two pairs: {w, w+4}, {w+8, w+12}
        int jj0 = w + 8*p, jj1 = w + 4 + 8*p;
        bool a0 = jj0 < jcnt, a1 = jj1 < jcnt;
        int jc0 = a0 ? jj0 : 0, jc1 = a1 ? jj1 : 0;
        int jv0 = j0 + jc0,   jv1 = j0 + jc1;
        const float* c0 = eat + (size_t)(g*R + jv0)*R*EDIM;
        const float* c1 = eat + (size_t)(g*R + jv1)*R*EDIM;
        float e0A[5], e0B[5], e1A[5], e1B[5];
#pragma unroll
        for (int e = 0; e < 5; ++e) {
            e0A[e] = c0[lane*EDIM + e];
            e0B[e] = c0[rb*EDIM + e];
            e1A[e] = c1[lane*EDIM + e];
            e1B[e] = c1[rb*EDIM + e];
        }
        float axr0 = axrg[g*R + jv0];
        float axr1 = axrg[g*R + jv1];
        float acc0A = 0.f, acc0B = 0.f, acc1A = 0.f, acc1B = 0.f;
#pragma unroll 4
        for (int c = 0; c < HID; ++c) {
            float4 qa = *(const float4*)&we_s[c][0];
            float2 qb = *(const float2*)&we_s[c][4];   // {We4, att}
            float xA = xls[lane][c];
            float xB = xls[rb][c];
            float u0 = xrs[jc0][c];
            float u1 = xrs[jc1][c];
            float z0A = xA + u0;
            z0A = fmaf(e0A[0],qa.x,z0A); z0A = fmaf(e0A[1],qa.y,z0A);
            z0A = fmaf(e0A[2],qa.z,z0A); z0A = fmaf(e0A[3],qa.w,z0A);
            z0A = fmaf(e0A[4],qb.x,z0A);
            acc0A = fmaf(__builtin_fabsf(z0A), qb.y, acc0A);
            float z0B = xB + u0;
            z0B = fmaf(e0B[0],qa.x,z0B); z0B = fmaf(e0B[1],qa.y,z0B);
            z0B = fmaf(e0B[2],qa.z,z0B); z0B = fmaf(e0B[3],qa.w,z0B);
            z0B = fmaf(e0B[4],qb.x,z0B);
            acc0B = fmaf(__builtin_fabsf(z0B), qb.y, acc0B);
            float z1A = xA + u1;
            z1A = fmaf(e1A[0],qa.x,z1A); z1A = fmaf(e1A[1],qa.y,z1A);
            z1A = fmaf(e1A[2],qa.z,z1A); z1A = fmaf(e1A[3],qa.w,z1A);
            z1A = fmaf(e1A[4],qb.x,z1A);
            acc1A = fmaf(__builtin_fabsf(z1A), qb.y, acc1A);
            float z1B = xB + u1;
            z1B = fmaf(e1B[0],qa.x,z1B); z1B = fmaf(e1B[1],qa.y,z1B);
            z1B = fmaf(e1B[2],qa.z,z1B); z1B = fmaf(e1B[3],qa.w,z1B);
            z1B = fmaf(e1B[4],qb.x,z1B);
            acc1B = fmaf(__builtin_fabsf(z1B), qb.y, acc1B);
        }
        // lrelu(z,0.2) = 0.6z + 0.4|z| => score = 0.6*L + 0.4*acc
        float L0A = axA + axr0, L0B = axB + axr0;
        L0A = fmaf(e0A[0],wasv0,L0A); L0A = fmaf(e0A[1],wasv1,L0A);
        L0A = fmaf(e0A[2],wasv2,L0A); L0A = fmaf(e0A[3],wasv3,L0A);
        L0A = fmaf(e0A[4],wasv4,L0A);
        L0B = fmaf(e0B[0],wasv0,L0B); L0B = fmaf(e0B[1],wasv1,L0B);
        L0B = fmaf(e0B[2],wasv2,L0B); L0B = fmaf(e0B[3],wasv3,L0B);
        L0B = fmaf(e0B[4],wasv4,L0B);
        float L1A = axA + axr1, L1B = axB + axr1;
        L1A = fmaf(e1A[0],wasv0,L1A); L1A = fmaf(e1A[1],wasv1,L1A);
        L1A = fmaf(e1A[2],wasv2,L1A); L1A = fmaf(e1A[3],wasv3,L1A);
        L1A = fmaf(e1A[4],wasv4,L1A);
        L1B = fmaf(e1B[0],wasv0,L1B); L1B = fmaf(e1B[1],wasv1,L1B);
        L1B = fmaf(e1B[2],wasv2,L1B); L1B = fmaf(e1B[3],wasv3,L1B);
        L1B = fmaf(e1B[4],wasv4,L1B);

        float s0A = fmaf(0.4f, acc0A, 0.6f*L0A);
        float s0B = vB ? fmaf(0.4f, acc0B, 0.6f*L0B) : -1e30f;
        float m0 = fmaxf(s0A, s0B);
#pragma unroll
        for (int msk = 32; msk >= 1; msk >>= 1) m0 = fmaxf(m0, __shfl_xor(m0, msk, 64));
        float x0A = __expf(s0A - m0);
        float x0B = vB ? __expf(s0B - m0) : 0.f;
        float sm0 = x0A + x0B;
#pragma unroll
        for (int msk = 32; msk >= 1; msk >>= 1) sm0 += __shfl_xor(sm0, msk, 64);
        float inv0 = 1.f / (sm0 + 1e-16f);
        ps[w][0][lane] = x0A * inv0;
        if (vB) ps[w][0][64 + lane] = x0B * inv0;

        float s1A = fmaf(0.4f, acc1A, 0.6f*L1A);
        float s1B = vB ? fmaf(0.4f, acc1B, 0.6f*L1B) : -1e30f;
        float m1 = fmaxf(s1A, s1B);
#pragma unroll
        for (int msk = 32; msk >= 1; msk >>= 1) m1 = fmaxf(m1, __shfl_xor(m1, msk, 64));
        float x1A = __expf(s1A - m1);
        float x1B = vB ? __expf(s1B - m1) : 0.f;
        float sm1 = x1A + x1B;
#pragma unroll
        for (int msk = 32; msk >= 1; msk >>= 1) sm1 += __shfl_xor(sm1, msk, 64);
        float inv1 = 1.f / (sm1 + 1e-16f);
        ps[w][1][lane] = x1A * inv1;
        if (vB) ps[w][1][64 + lane] = x1B * inv1;

        // paired aggregation: same-wave LDS produce->consume, shared x reads
        float o0 = 0.f, o1 = 0.f;
        for (int i = 0; i < R; i += 4) {
            float4 p0v = *(const float4*)&ps[w][0][i];
            float4 p1v = *(const float4*)&ps[w][1][i];
            float x0 = xls[i  ][lane], x1 = xls[i+1][lane];
            float x2 = xls[i+2][lane], x3 = xls[i+3][lane];
            o0 = fmaf(p0v.x,x0,o0); o0 = fmaf(p0v.y,x1,o0);
            o0 = fmaf(p0v.z,x2,o0); o0 = fmaf(p0v.w,x3,o0);
            o1 = fmaf(p1v.x,x0,o1); o1 = fmaf(p1v.y,x1,o1);
            o1 = fmaf(p1v.z,x2,o1); o1 = fmaf(p1v.w,x3,o1);
        }
        if (a0) hout[hbase + (size_t)jv0*HID + lane] = fmaxf(o0 + biasv, 0.f);
        if (a1) hout[hbase + (size_t)jv1*HID + lane] = fmaxf(o1 + biasv, 0.f);
    }
}

// ---------------- pooling ----------------
__global__ __launch_bounds__(256) void k_pool_score(
    const float* __restrict__ h, const float* __restrict__ W1,
    const float* __restrict__ b1, const float* __restrict__ w2,
    float* __restrict__ scores) {
    int w = threadIdx.x >> 6, lane = threadIdx.x & 63;
    int n = blockIdx.x*4 + w;
    __shared__ float hr[4][68];
    hr[w][lane] = h[(size_t)n*HID + lane];
    float acc = b1[lane];
#pragma unroll
    for (int k = 0; k < HID; k += 4) {
        float4 q = *(const float4*)&hr[w][k];
        acc = fmaf(q.x, W1[(k  )*HID + lane], acc);
        acc = fmaf(q.y, W1[(k+1)*HID + lane], acc);
        acc = fmaf(q.z, W1[(k+2)*HID + lane], acc);
        acc = fmaf(q.w, W1[(k+3)*HID + lane], acc);
    }
    float p = tanhf(acc) * w2[lane];
    p = waveReduceSum(p);
    if (lane == 0) scores[n] = p;
}

__global__ __launch_bounds__(1024) void k_pool_reduce(
    const float* __restrict__ scores, float* __restrict__ ms) {
    __shared__ float red[1024];
    int tid = threadIdx.x;
    float m = -1e30f;
    for (int i = tid; i < NN; i += 1024) m = fmaxf(m, scores[i]);
    red[tid] = m;
    __syncthreads();
    for (int s = 512; s > 0; s >>= 1) {
        if (tid < s) red[tid] = fmaxf(red[tid], red[tid+s]);
        __syncthreads();
    }
    float mx = red[0];
    __syncthreads();
    float sum = 0.f;
    for (int i = tid; i < NN; i += 1024) sum += __expf(scores[i] - mx);
    red[tid] = sum;
    __syncthreads();
    for (int s = 512; s > 0; s >>= 1) {
        if (tid < s) red[tid] += red[tid+s];
        __syncthreads();
    }
    if (tid == 0) { ms[0] = mx; ms[1] = red[0]; }
}

__global__ __launch_bounds__(64) void k_pool_final(
    const float* __restrict__ h, const float* __restrict__ scores,
    const float* __restrict__ ms,
    const float* __restrict__ lin1W, const float* __restrict__ lin1b,
    const float* __restrict__ lin2W, const float* __restrict__ lin2b,
    float* __restrict__ out) {
    int g = blockIdx.x, c = threadIdx.x;
    float mx = ms[0], inv = 1.f / ms[1];
    float pc = 0.f;
    int nb = g*R;
    for (int r = 0; r < R; ++r) {
        float wv = __expf(scores[nb + r] - mx) * inv;
        pc = fmaf(h[(size_t)(nb + r)*HID + c], wv, pc);
    }
    __shared__ float pl[HID];
    __shared__ float t[INCH];
    pl[c] = pc;
    __syncthreads();
    for (int k = c; k < INCH; k += 64) {
        float acc = lin1b[k];
#pragma unroll 8
        for (int q = 0; q < HID; ++q) acc = fmaf(pl[q], lin1W[q*INCH + k], acc);
        t[k] = fmaxf(acc, 0.f);
    }
    __syncthreads();
    if (c < 2) {
        float o = lin2b[c];
        for (int k = 0; k < INCH; ++k) o = fmaf(t[k], lin2W[k*2 + c], o);
        out[g*2 + c] = o;
    }
}

extern "C" void kernel_launch(void* const* d_in, const int* in_sizes, int n_in,
                              void* d_out, int out_size, void* d_ws, size_t ws_size,
                              hipStream_t stream) {
    (void)in_sizes; (void)n_in; (void)out_size; (void)ws_size;
    const float* x        = (const float*)d_in[0];
    const float* edge_attr= (const float*)d_in[1];
    const float* emb      = (const float*)d_in[2];
    const float* enc_W    = (const float*)d_in[3];
    const float* enc_b    = (const float*)d_in[4];
    const float* bn_g     = (const float*)d_in[5];
    const float* bn_b     = (const float*)d_in[6];
    const float* gine_We  = (const float*)d_in[7];
    const float* gine_be  = (const float*)d_in[8];
    const float* gine_W1  = (const float*)d_in[9];
    const float* gine_b1  = (const float*)d_in[10];
    const float* gine_W2  = (const float*)d_in[11];
    const float* gine_b2  = (const float*)d_in[12];
    const float* gat_Wl   = (const float*)d_in[13];
    const float* gat_bl   = (const float*)d_in[14];
    const float* gat_Wr   = (const float*)d_in[15];
    const float* gat_br   = (const float*)d_in[16];
    const float* gat_att  = (const float*)d_in[17];
    const float* gat_We   = (const float*)d_in[18];
    const float* gat_bias = (const float*)d_in[19];
    const float* pool_W1  = (const float*)d_in[20];
    const float* pool_b1  = (const float*)d_in[21];
    const float* pool_w2  = (const float*)d_in[22];
    const float* lin1_W   = (const float*)d_in[23];
    const float* lin1_b   = (const float*)d_in[24];
    const float* lin2_W   = (const float*)d_in[25];
    const float* lin2_b   = (const float*)d_in[26];
    const int*   group_ids= (const int*)d_in[29];
    float* out = (float*)d_out;

    float* w = (float*)d_ws;
    float* eat      = w;                            // R2*G*EDIM
    float* hA       = eat + (size_t)R2*G*EDIM;      // NN*HID
    float* hB       = hA + (size_t)NN*HID;
    float* xlb      = hB + (size_t)NN*HID;
    float* xrb      = xlb + (size_t)NN*HID;
    float* axl      = xrb + (size_t)NN*HID;         // NN
    float* axr      = axl + NN;                     // NN
    float* scores   = axr + NN;                     // NN
    float* partials = scores + NN;                  // 232*128
    float* stats    = partials + (NN/64)*128;       // 128
    float* pms      = stats + 128;                  // 2

    k_etr<<<G*16, 256, 0, stream>>>(edge_attr, eat);
    k_encode<<<NN/4, 256, 0, stream>>>(x, emb, group_ids, enc_W, enc_b, hA);
    k_stats_partial<<<NN/64, 256, 0, stream>>>(hA, partials);
    k_stats_final<<<1, 64, 0, stream>>>(partials, bn_g, bn_b, stats);
    k_gine<<<G*8, 256, 0, stream>>>(hA, stats, eat, gine_We, gine_be,
                                    gine_W1, gine_b1, gine_W2, gine_b2, hB);
    // GAT layer 0: hB -> hA
    k_xlxr<<<NN/4, 256, 0, stream>>>(hB, gat_Wl, gat_bl, gat_Wr, gat_br,
                                     gat_att, xlb, xrb, axl, axr);
    k_gat<<<G*8, 256, 0, stream>>>(xlb, xrb, axl, axr, eat, gat_We,
                                   gat_att, gat_bias, hA);
    // GAT layer 1: hA -> hB
    k_xlxr<<<NN/4, 256, 0, stream>>>(hA, gat_Wl + HID*HID, gat_bl + HID,
                                     gat_Wr + HID*HID, gat_br + HID,
                                     gat_att + HID, xlb, xrb, axl, axr);
    k_gat<<<G*8, 256, 0, stream>>>(xlb, xrb, axl, axr, eat, gat_We + EDIM*HID,
                                   gat_att + HID, gat_bias + HID, hB);
    // pooling + head
    k_pool_score<<<NN/4, 256, 0, stream>>>(hB, pool_W1, pool_b1, pool_w2, scores);
    k_pool_reduce<<<1, 1024, 0, stream>>>(scores, pms);
    k_pool_final<<<G, 64, 0, stream>>>(hB, scores, pms, lin1_W, lin1_b,
                                       lin2_W, lin2_b, out);
}

// Round 8
// 267.994 us; speedup vs baseline: 3.4283x; 1.3174x over previous
//
#include <hip/hip_runtime.h>
#include <math.h>

#define R    116
#define R2   (116*116)
#define G    128
#define NN   (R*G)      // 14848 nodes
#define HID  64
#define EDIM 5
#define INCH 116
#define EMBD 16

__device__ __forceinline__ float waveReduceSum(float v) {
#pragma unroll
    for (int m = 32; m >= 1; m >>= 1) v += __shfl_xor(v, m, 64);
    return v;
}

// ---------------- edge-attr transpose: eat[g][j][i][e] = ea[g][i][j][e] -------
__global__ __launch_bounds__(256) void k_etr(
    const float* __restrict__ ea, float* __restrict__ eat) {
    int b = blockIdx.x;
    int g = b >> 4;
    int t = b & 15;
    int i0 = (t >> 2) << 5, j0 = (t & 3) << 5;
    int ni = min(32, R - i0), nj = min(32, R - j0);
    __shared__ float tile[32][165];
    const float* src = ea + ((size_t)(g*R + i0)*R + j0)*EDIM;
    int tot = ni * nj * EDIM;
    for (int idx = threadIdx.x; idx < tot; idx += 256) {
        int ii = idx / (nj*EDIM);
        int rem = idx - ii*(nj*EDIM);
        tile[ii][rem] = src[(size_t)ii*R*EDIM + rem];
    }
    __syncthreads();
    float* dst = eat + ((size_t)(g*R + j0)*R + i0)*EDIM;
    int tot2 = nj * ni * EDIM;
    for (int idx = threadIdx.x; idx < tot2; idx += 256) {
        int jj = idx / (ni*EDIM);
        int rem = idx - jj*(ni*EDIM);     // ii*5 + e
        int ii = rem / EDIM, e = rem - ii*EDIM;
        dst[(size_t)jj*R*EDIM + rem] = tile[ii][jj*EDIM + e];
    }
}

// ---------------- prepack GAT per-channel tables + We@att dots ----------------
__global__ __launch_bounds__(64) void k_prep(
    const float* __restrict__ We, const float* __restrict__ att,
    float* __restrict__ wepack, float* __restrict__ was2) {
    int l = blockIdx.x, c = threadIdx.x;
    const float* Wl = We + l*EDIM*HID;
    const float* al = att + l*HID;
    float g0=Wl[c], g1=Wl[64+c], g2=Wl[128+c], g3=Wl[192+c], g4=Wl[256+c];
    float at = al[c];
    float* wp = wepack + l*HID*8 + c*8;
    wp[0]=g0; wp[1]=g1; wp[2]=g2; wp[3]=g3; wp[4]=g4; wp[5]=at;
    wp[6]=0.f; wp[7]=0.f;
    float p0 = waveReduceSum(g0*at);
    float p1 = waveReduceSum(g1*at);
    float p2 = waveReduceSum(g2*at);
    float p3 = waveReduceSum(g3*at);
    float p4 = waveReduceSum(g4*at);
    if (c == 0) {
        float* ws = was2 + l*8;
        ws[0]=p0; ws[1]=p1; ws[2]=p2; ws[3]=p3; ws[4]=p4;
    }
}

// ---------------- encode: h = relu([x, emb[gid]] @ W + b), 4 nodes/block ------
__global__ __launch_bounds__(256) void k_encode(
    const float* __restrict__ x, const float* __restrict__ emb,
    const int* __restrict__ group_ids,
    const float* __restrict__ W, const float* __restrict__ bvec,
    float* __restrict__ h) {
    int w = threadIdx.x >> 6, lane = threadIdx.x & 63;
    int n = blockIdx.x*4 + w;
    __shared__ float xin[4][136];
    for (int idx = lane; idx < INCH; idx += 64) xin[w][idx] = x[(size_t)n*INCH + idx];
    if (lane < EMBD) xin[w][INCH + lane] = emb[group_ids[n]*EMBD + lane];
    float acc = bvec[lane];
#pragma unroll
    for (int k = 0; k < INCH + EMBD; k += 4) {
        float4 q = *(const float4*)&xin[w][k];
        acc = fmaf(q.x, W[(k  )*HID + lane], acc);
        acc = fmaf(q.y, W[(k+1)*HID + lane], acc);
        acc = fmaf(q.z, W[(k+2)*HID + lane], acc);
        acc = fmaf(q.w, W[(k+3)*HID + lane], acc);
    }
    h[(size_t)n*HID + lane] = fmaxf(acc, 0.f);
}

// ---------------- batchnorm stats (two-stage, deterministic) ----------------
__global__ __launch_bounds__(256) void k_stats_partial(
    const float* __restrict__ h, float* __restrict__ partials) {
    int b = blockIdx.x;
    int tid = threadIdx.x;
    int c = tid & 63, r0 = tid >> 6;
    float s = 0.f, s2 = 0.f;
    int row0 = b*64;
#pragma unroll
    for (int k = 0; k < 16; ++k) {
        float v = h[(size_t)(row0 + r0 + 4*k)*HID + c];
        s += v; s2 += v*v;
    }
    __shared__ float ls[256], l2[256];
    ls[tid] = s; l2[tid] = s2;
    __syncthreads();
    if (tid < 64) {
        s  = ls[tid] + ls[tid+64] + ls[tid+128] + ls[tid+192];
        s2 = l2[tid] + l2[tid+64] + l2[tid+128] + l2[tid+192];
        partials[b*128 + tid]      = s;
        partials[b*128 + 64 + tid] = s2;
    }
}

__global__ __launch_bounds__(64) void k_stats_final(
    const float* __restrict__ partials, const float* __restrict__ gam,
    const float* __restrict__ bet, float* __restrict__ stats) {
    int c = threadIdx.x;
    float s = 0.f, s2 = 0.f;
    for (int b = 0; b < NN/64; ++b) {
        s  += partials[b*128 + c];
        s2 += partials[b*128 + 64 + c];
    }
    float mu  = s / (float)NN;
    float var = s2 / (float)NN - mu*mu;
    float rs  = rsqrtf(var + 1e-5f);
    float sc  = rs * gam[c];
    stats[c]      = sc;
    stats[64 + c] = bet[c] - mu*sc;
}

// ------- GINE: 8 dsts/wave, SCALAR edge-strip loads from original layout -----
__global__ __launch_bounds__(256) void k_gine(
    const float* __restrict__ h, const float* __restrict__ stats,
    const float* __restrict__ ea,
    const float* __restrict__ We, const float* __restrict__ be,
    const float* __restrict__ W1, const float* __restrict__ b1,
    const float* __restrict__ W2, const float* __restrict__ b2,
    float* __restrict__ hout) {
    int b = blockIdx.x;
    int g = b & (G-1), q = b >> 7;         // 4 quarters
    int tid = threadIdx.x, w = tid >> 6, lane = tid & 63;
    int j0 = min(q*32 + w*8, R - 8);       // clamp: overlap waves write identical values
    __shared__ float hs[R][64];
    __shared__ float t1s[4][68];
    size_t hbase = (size_t)g*R*HID;
    float scv = stats[lane], shv = stats[64 + lane];
    for (int idx = tid; idx < R*HID; idx += 256)
        hs[idx>>6][lane] = fmaf(h[hbase + idx], scv, shv);
    float w0=We[lane], w1v=We[64+lane], w2v=We[128+lane],
          w3v=We[192+lane], w4v=We[256+lane], bec=be[lane];
    __syncthreads();

    float acc[8] = {0.f,0.f,0.f,0.f,0.f,0.f,0.f,0.f};
    int sbase = __builtin_amdgcn_readfirstlane((g*R*R + j0)*EDIM);
    for (int i = 0; i < R; ++i) {
        float hv = hs[i][lane];
        const float* sp = ea + sbase + i*(R*EDIM);   // uniform -> scalar loads
#pragma unroll
        for (int j = 0; j < 8; ++j) {
            float ew = bec;
            ew = fmaf(sp[j*5+0], w0,  ew);
            ew = fmaf(sp[j*5+1], w1v, ew);
            ew = fmaf(sp[j*5+2], w2v, ew);
            ew = fmaf(sp[j*5+3], w3v, ew);
            ew = fmaf(sp[j*5+4], w4v, ew);
            acc[j] += fmaxf(hv + ew, 0.f);
        }
    }
#pragma unroll
    for (int j = 0; j < 8; ++j) {
        int jd = j0 + j;
        float h1 = hs[jd][lane] + acc[j];
        t1s[w][lane] = h1;                 // same-wave in-order LDS
        float a1 = b1[lane];
#pragma unroll
        for (int k = 0; k < HID; k += 4) {
            float4 tq = *(const float4*)&t1s[w][k];
            a1 = fmaf(tq.x, W1[(k  )*HID + lane], a1);
            a1 = fmaf(tq.y, W1[(k+1)*HID + lane], a1);
            a1 = fmaf(tq.z, W1[(k+2)*HID + lane], a1);
            a1 = fmaf(tq.w, W1[(k+3)*HID + lane], a1);
        }
        t1s[w][lane] = fmaxf(a1, 0.f);
        float a2 = b2[lane];
#pragma unroll
        for (int k = 0; k < HID; k += 4) {
            float4 tq = *(const float4*)&t1s[w][k];
            a2 = fmaf(tq.x, W2[(k  )*HID + lane], a2);
            a2 = fmaf(tq.y, W2[(k+1)*HID + lane], a2);
            a2 = fmaf(tq.z, W2[(k+2)*HID + lane], a2);
            a2 = fmaf(tq.w, W2[(k+3)*HID + lane], a2);
        }
        hout[hbase + (size_t)jd*HID + lane] = fmaxf(a2, 0.f);
    }
}

// ---------------- GAT: xl/xr projections + att-dot precompute ----------------
__global__ __launch_bounds__(256) void k_xlxr(
    const float* __restrict__ h,
    const float* __restrict__ Wl, const float* __restrict__ bl,
    const float* __restrict__ Wr, const float* __restrict__ br,
    const float* __restrict__ att,
    float* __restrict__ xl, float* __restrict__ xr,
    float* __restrict__ axl, float* __restrict__ axr) {
    int w = threadIdx.x >> 6, lane = threadIdx.x & 63;
    int n = blockIdx.x*4 + w;
    __shared__ float hr[4][68];
    hr[w][lane] = h[(size_t)n*HID + lane];
    float aL = bl[lane], aR = br[lane];
#pragma unroll
    for (int k = 0; k < HID; k += 4) {
        float4 q = *(const float4*)&hr[w][k];
        aL = fmaf(q.x, Wl[(k  )*HID + lane], aL);
        aR = fmaf(q.x, Wr[(k  )*HID + lane], aR);
        aL = fmaf(q.y, Wl[(k+1)*HID + lane], aL);
        aR = fmaf(q.y, Wr[(k+1)*HID + lane], aR);
        aL = fmaf(q.z, Wl[(k+2)*HID + lane], aL);
        aR = fmaf(q.z, Wr[(k+2)*HID + lane], aR);
        aL = fmaf(q.w, Wl[(k+3)*HID + lane], aL);
        aR = fmaf(q.w, Wr[(k+3)*HID + lane], aR);
    }
    xl[(size_t)n*HID + lane] = aL;
    xr[(size_t)n*HID + lane] = aR;
    float at = att[lane];
    float pL = waveReduceSum(aL * at);
    float pR = waveReduceSum(aR * at);
    if (lane == 0) { axl[n] = pL; axr[n] = pR; }
}

// ------- GAT: r5 skeleton + scalar wepack/xr loads, b64 xls reads ------------
__global__ __launch_bounds__(256) void k_gat(
    const float* __restrict__ xl, const float* __restrict__ xr,
    const float* __restrict__ axlg, const float* __restrict__ axrg,
    const float* __restrict__ eat, const float* __restrict__ wepack,
    const float* __restrict__ wasg, const float* __restrict__ bias,
    float* __restrict__ hout) {
    int b = blockIdx.x;
    int g = b & (G-1), chunk = b >> 7;     // 8 chunks x 15 dsts
    int j0 = chunk*15, jcnt = min(15, R - j0);
    int tid = threadIdx.x, w = tid >> 6, lane = tid & 63;
    __shared__ float xls[R][66];           // stride 66: 8B-aligned rows, 2-way banks
    __shared__ float ps[4][120];
    size_t hbase = (size_t)g*R*HID;
    for (int idx = tid; idx < R*HID; idx += 256)
        xls[idx>>6][idx&63] = xl[hbase + idx];
    float biasv = bias[lane];
    float wasv0 = wasg[0], wasv1 = wasg[1], wasv2 = wasg[2],
          wasv3 = wasg[3], wasv4 = wasg[4];
    bool vB = lane < (R - 64);
    int rb = vB ? (64 + lane) : lane;      // clamped B-row
    float axA = axlg[g*R + lane];
    float axB = axlg[g*R + rb];
    __syncthreads();

    for (int jj = w; jj < jcnt; jj += 4) {
        int j = j0 + jj;
        const float* colp = eat + (size_t)(g*R + j)*R*EDIM;
        float eA[5], eB[5];
#pragma unroll
        for (int e = 0; e < 5; ++e) {
            eA[e] = colp[lane*EDIM + e];
            eB[e] = colp[rb*EDIM + e];
        }
        const float* xrp = xr + hbase + (size_t)j*HID;   // uniform -> scalar
        float axrj = axrg[g*R + j];                      // uniform
        float accA = 0.f, accB = 0.f;
#pragma unroll 4
        for (int c = 0; c < HID; c += 2) {
            float2 xA2 = *(const float2*)&xls[lane][c];
            float2 xB2 = *(const float2*)&xls[rb][c];
            {
                const float* wp = wepack + c*8;          // uniform -> scalar
                float u = xrp[c];
                float zA = xA2.x + u;
                zA = fmaf(eA[0],wp[0],zA); zA = fmaf(eA[1],wp[1],zA);
                zA = fmaf(eA[2],wp[2],zA); zA = fmaf(eA[3],wp[3],zA);
                zA = fmaf(eA[4],wp[4],zA);
                accA = fmaf(__builtin_fabsf(zA), wp[5], accA);
                float zB = xB2.x + u;
                zB = fmaf(eB[0],wp[0],zB); zB = fmaf(eB[1],wp[1],zB);
                zB = fmaf(eB[2],wp[2],zB); zB = fmaf(eB[3],wp[3],zB);
                zB = fmaf(eB[4],wp[4],zB);
                accB = fmaf(__builtin_fabsf(zB), wp[5], accB);
            }
            {
                const float* wp = wepack + (c+1)*8;
                float u = xrp[c+1];
                float zA = xA2.y + u;
                zA = fmaf(eA[0],wp[0],zA); zA = fmaf(eA[1],wp[1],zA);
                zA = fmaf(eA[2],wp[2],zA); zA = fmaf(eA[3],wp[3],zA);
                zA = fmaf(eA[4],wp[4],zA);
                accA = fmaf(__builtin_fabsf(zA), wp[5], accA);
                float zB = xB2.y + u;
                zB = fmaf(eB[0],wp[0],zB); zB = fmaf(eB[1],wp[1],zB);
                zB = fmaf(eB[2],wp[2],zB); zB = fmaf(eB[3],wp[3],zB);
                zB = fmaf(eB[4],wp[4],zB);
                accB = fmaf(__builtin_fabsf(zB), wp[5], accB);
            }
        }
        // linear part: L = axl + axr + ea . (We@att)
        float LA = axA + axrj, LB = axB + axrj;
        LA = fmaf(eA[0],wasv0,LA); LA = fmaf(eA[1],wasv1,LA);
        LA = fmaf(eA[2],wasv2,LA); LA = fmaf(eA[3],wasv3,LA);
        LA = fmaf(eA[4],wasv4,LA);
        LB = fmaf(eB[0],wasv0,LB); LB = fmaf(eB[1],wasv1,LB);
        LB = fmaf(eB[2],wasv2,LB); LB = fmaf(eB[3],wasv3,LB);
        LB = fmaf(eB[4],wasv4,LB);
        // lrelu(z,0.2) = 0.6z + 0.4|z| => score = 0.6*L + 0.4*acc
        float sA = fmaf(0.4f, accA, 0.6f*LA);
        float sB = vB ? fmaf(0.4f, accB, 0.6f*LB) : -1e30f;
        float m = fmaxf(sA, sB);
#pragma unroll
        for (int msk = 32; msk >= 1; msk >>= 1) m = fmaxf(m, __shfl_xor(m, msk, 64));
        float eAx = __expf(sA - m);
        float eBx = vB ? __expf(sB - m) : 0.f;
        float s = eAx + eBx;
#pragma unroll
        for (int msk = 32; msk >= 1; msk >>= 1) s += __shfl_xor(s, msk, 64);
        float inv = 1.f / (s + 1e-16f);
        ps[w][lane] = eAx * inv;
        if (vB) ps[w][64 + lane] = eBx * inv;
        // same-wave produce->consume
        float o = 0.f;
#pragma unroll 4
        for (int i = 0; i < R; i += 4) {
            float4 p4 = *(const float4*)&ps[w][i];
            o = fmaf(p4.x, xls[i  ][lane], o);
            o = fmaf(p4.y, xls[i+1][lane], o);
            o = fmaf(p4.z, xls[i+2][lane], o);
            o = fmaf(p4.w, xls[i+3][lane], o);
        }
        hout[hbase + (size_t)j*HID + lane] = fmaxf(o + biasv, 0.f);
    }
}

// ---------------- pooling ----------------
__global__ __launch_bounds__(256) void k_pool_score(
    const float* __restrict__ h, const float* __restrict__ W1,
    const float* __restrict__ b1, const float* __restrict__ w2,
    float* __restrict__ scores) {
    int w = threadIdx.x >> 6, lane = threadIdx.x & 63;
    int n = blockIdx.x*4 + w;
    __shared__ float hr[4][68];
    hr[w][lane] = h[(size_t)n*HID + lane];
    float acc = b1[lane];
#pragma unroll
    for (int k = 0; k < HID; k += 4) {
        float4 q = *(const float4*)&hr[w][k];
        acc = fmaf(q.x, W1[(k  )*HID + lane], acc);
        acc = fmaf(q.y, W1[(k+1)*HID + lane], acc);
        acc = fmaf(q.z, W1[(k+2)*HID + lane], acc);
        acc = fmaf(q.w, W1[(k+3)*HID + lane], acc);
    }
    float p = tanhf(acc) * w2[lane];
    p = waveReduceSum(p);
    if (lane == 0) scores[n] = p;
}

__global__ __launch_bounds__(1024) void k_pool_reduce(
    const float* __restrict__ scores, float* __restrict__ ms) {
    __shared__ float red[1024];
    int tid = threadIdx.x;
    float m = -1e30f;
    for (int i = tid; i < NN; i += 1024) m = fmaxf(m, scores[i]);
    red[tid] = m;
    __syncthreads();
    for (int s = 512; s > 0; s >>= 1) {
        if (tid < s) red[tid] = fmaxf(red[tid], red[tid+s]);
        __syncthreads();
    }
    float mx = red[0];
    __syncthreads();
    float sum = 0.f;
    for (int i = tid; i < NN; i += 1024) sum += __expf(scores[i] - mx);
    red[tid] = sum;
    __syncthreads();
    for (int s = 512; s > 0; s >>= 1) {
        if (tid < s) red[tid] += red[tid+s];
        __syncthreads();
    }
    if (tid == 0) { ms[0] = mx; ms[1] = red[0]; }
}

__global__ __launch_bounds__(64) void k_pool_final(
    const float* __restrict__ h, const float* __restrict__ scores,
    const float* __restrict__ ms,
    const float* __restrict__ lin1W, const float* __restrict__ lin1b,
    const float* __restrict__ lin2W, const float* __restrict__ lin2b,
    float* __restrict__ out) {
    int g = blockIdx.x, c = threadIdx.x;
    float mx = ms[0], inv = 1.f / ms[1];
    float pc = 0.f;
    int nb = g*R;
    for (int r = 0; r < R; ++r) {
        float wv = __expf(scores[nb + r] - mx) * inv;
        pc = fmaf(h[(size_t)(nb + r)*HID + c], wv, pc);
    }
    __shared__ float pl[HID];
    __shared__ float t[INCH];
    pl[c] = pc;
    __syncthreads();
    for (int k = c; k < INCH; k += 64) {
        float acc = lin1b[k];
#pragma unroll 8
        for (int q = 0; q < HID; ++q) acc = fmaf(pl[q], lin1W[q*INCH + k], acc);
        t[k] = fmaxf(acc, 0.f);
    }
    __syncthreads();
    if (c < 2) {
        float o = lin2b[c];
        for (int k = 0; k < INCH; ++k) o = fmaf(t[k], lin2W[k*2 + c], o);
        out[g*2 + c] = o;
    }
}

extern "C" void kernel_launch(void* const* d_in, const int* in_sizes, int n_in,
                              void* d_out, int out_size, void* d_ws, size_t ws_size,
                              hipStream_t stream) {
    (void)in_sizes; (void)n_in; (void)out_size; (void)ws_size;
    const float* x        = (const float*)d_in[0];
    const float* edge_attr= (const float*)d_in[1];
    const float* emb      = (const float*)d_in[2];
    const float* enc_W    = (const float*)d_in[3];
    const float* enc_b    = (const float*)d_in[4];
    const float* bn_g     = (const float*)d_in[5];
    const float* bn_b     = (const float*)d_in[6];
    const float* gine_We  = (const float*)d_in[7];
    const float* gine_be  = (const float*)d_in[8];
    const float* gine_W1  = (const float*)d_in[9];
    const float* gine_b1  = (const float*)d_in[10];
    const float* gine_W2  = (const float*)d_in[11];
    const float* gine_b2  = (const float*)d_in[12];
    const float* gat_Wl   = (const float*)d_in[13];
    const float* gat_bl   = (const float*)d_in[14];
    const float* gat_Wr   = (const float*)d_in[15];
    const float* gat_br   = (const float*)d_in[16];
    const float* gat_att  = (const float*)d_in[17];
    const float* gat_We   = (const float*)d_in[18];
    const float* gat_bias = (const float*)d_in[19];
    const float* pool_W1  = (const float*)d_in[20];
    const float* pool_b1  = (const float*)d_in[21];
    const float* pool_w2  = (const float*)d_in[22];
    const float* lin1_W   = (const float*)d_in[23];
    const float* lin1_b   = (const float*)d_in[24];
    const float* lin2_W   = (const float*)d_in[25];
    const float* lin2_b   = (const float*)d_in[26];
    const int*   group_ids= (const int*)d_in[29];
    float* out = (float*)d_out;

    float* w = (float*)d_ws;
    float* eat      = w;                            // R2*G*EDIM
    float* hA       = eat + (size_t)R2*G*EDIM;      // NN*HID
    float* hB       = hA + (size_t)NN*HID;
    float* xlb      = hB + (size_t)NN*HID;
    float* xrb      = xlb + (size_t)NN*HID;
    float* axl      = xrb + (size_t)NN*HID;         // NN
    float* axr      = axl + NN;                     // NN
    float* scores   = axr + NN;                     // NN
    float* partials = scores + NN;                  // 232*128
    float* stats    = partials + (NN/64)*128;       // 128
    float* pms      = stats + 128;                  // 2
    float* wepack   = pms + 2;                      // 2*64*8
    float* was2     = wepack + 2*HID*8;             // 2*8

    k_etr<<<G*16, 256, 0, stream>>>(edge_attr, eat);
    k_prep<<<2, 64, 0, stream>>>(gat_We, gat_att, wepack, was2);
    k_encode<<<NN/4, 256, 0, stream>>>(x, emb, group_ids, enc_W, enc_b, hA);
    k_stats_partial<<<NN/64, 256, 0, stream>>>(hA, partials);
    k_stats_final<<<1, 64, 0, stream>>>(partials, bn_g, bn_b, stats);
    k_gine<<<G*4, 256, 0, stream>>>(hA, stats, edge_attr, gine_We, gine_be,
                                    gine_W1, gine_b1, gine_W2, gine_b2, hB);
    // GAT layer 0: hB -> hA
    k_xlxr<<<NN/4, 256, 0, stream>>>(hB, gat_Wl, gat_bl, gat_Wr, gat_br,
                                     gat_att, xlb, xrb, axl, axr);
    k_gat<<<G*8, 256, 0, stream>>>(xlb, xrb, axl, axr, eat, wepack,
                                   was2, gat_bias, hA);
    // GAT layer 1: hA -> hB
    k_xlxr<<<NN/4, 256, 0, stream>>>(hA, gat_Wl + HID*HID, gat_bl + HID,
                                     gat_Wr + HID*HID, gat_br + HID,
                                     gat_att + HID, xlb, xrb, axl, axr);
    k_gat<<<G*8, 256, 0, stream>>>(xlb, xrb, axl, axr, eat, wepack + HID*8,
                                   was2 + 8, gat_bias + HID, hB);
    // pooling + head
    k_pool_score<<<NN/4, 256, 0, stream>>>(hB, pool_W1, pool_b1, pool_w2, scores);
    k_pool_reduce<<<1, 1024, 0, stream>>>(scores, pms);
    k_pool_final<<<G, 64, 0, stream>>>(hB, scores, pms, lin1_W, lin1_b,
                                       lin2_W, lin2_b, out);
}

// Round 9
// 267.903 us; speedup vs baseline: 3.4295x; 1.0003x over previous
//
#include <hip/hip_runtime.h>
#include <math.h>

#define R    116
#define R2   (116*116)
#define G    128
#define NN   (R*G)      // 14848 nodes
#define HID  64
#define EDIM 5
#define INCH 116
#define EMBD 16

__device__ __forceinline__ float waveReduceSum(float v) {
#pragma unroll
    for (int m = 32; m >= 1; m >>= 1) v += __shfl_xor(v, m, 64);
    return v;
}

// ---------------- edge-attr transpose: eat[g][j][i][e] = ea[g][i][j][e] -------
__global__ __launch_bounds__(256) void k_etr(
    const float* __restrict__ ea, float* __restrict__ eat) {
    int b = blockIdx.x;
    int g = b >> 4;
    int t = b & 15;
    int i0 = (t >> 2) << 5, j0 = (t & 3) << 5;
    int ni = min(32, R - i0), nj = min(32, R - j0);
    __shared__ float tile[32][165];
    const float* src = ea + ((size_t)(g*R + i0)*R + j0)*EDIM;
    int tot = ni * nj * EDIM;
    for (int idx = threadIdx.x; idx < tot; idx += 256) {
        int ii = idx / (nj*EDIM);
        int rem = idx - ii*(nj*EDIM);
        tile[ii][rem] = src[(size_t)ii*R*EDIM + rem];
    }
    __syncthreads();
    float* dst = eat + ((size_t)(g*R + j0)*R + i0)*EDIM;
    int tot2 = nj * ni * EDIM;
    for (int idx = threadIdx.x; idx < tot2; idx += 256) {
        int jj = idx / (ni*EDIM);
        int rem = idx - jj*(ni*EDIM);     // ii*5 + e
        int ii = rem / EDIM, e = rem - ii*EDIM;
        dst[(size_t)jj*R*EDIM + rem] = tile[ii][jj*EDIM + e];
    }
}

// ---------------- prepack GAT per-channel tables + We@att dots ----------------
__global__ __launch_bounds__(64) void k_prep(
    const float* __restrict__ We, const float* __restrict__ att,
    float* __restrict__ wepack, float* __restrict__ was2) {
    int l = blockIdx.x, c = threadIdx.x;
    const float* Wl = We + l*EDIM*HID;
    const float* al = att + l*HID;
    float g0=Wl[c], g1=Wl[64+c], g2=Wl[128+c], g3=Wl[192+c], g4=Wl[256+c];
    float at = al[c];
    float* wp = wepack + l*HID*8 + c*8;
    wp[0]=g0; wp[1]=g1; wp[2]=g2; wp[3]=g3; wp[4]=g4; wp[5]=at;
    wp[6]=0.f; wp[7]=0.f;
    float p0 = waveReduceSum(g0*at);
    float p1 = waveReduceSum(g1*at);
    float p2 = waveReduceSum(g2*at);
    float p3 = waveReduceSum(g3*at);
    float p4 = waveReduceSum(g4*at);
    if (c == 0) {
        float* ws = was2 + l*8;
        ws[0]=p0; ws[1]=p1; ws[2]=p2; ws[3]=p3; ws[4]=p4;
    }
}

// ---------------- encode: h = relu([x, emb[gid]] @ W + b), 4 nodes/block ------
__global__ __launch_bounds__(256) void k_encode(
    const float* __restrict__ x, const float* __restrict__ emb,
    const int* __restrict__ group_ids,
    const float* __restrict__ W, const float* __restrict__ bvec,
    float* __restrict__ h) {
    int w = threadIdx.x >> 6, lane = threadIdx.x & 63;
    int n = blockIdx.x*4 + w;
    __shared__ float xin[4][136];
    for (int idx = lane; idx < INCH; idx += 64) xin[w][idx] = x[(size_t)n*INCH + idx];
    if (lane < EMBD) xin[w][INCH + lane] = emb[group_ids[n]*EMBD + lane];
    float acc = bvec[lane];
#pragma unroll
    for (int k = 0; k < INCH + EMBD; k += 4) {
        float4 q = *(const float4*)&xin[w][k];
        acc = fmaf(q.x, W[(k  )*HID + lane], acc);
        acc = fmaf(q.y, W[(k+1)*HID + lane], acc);
        acc = fmaf(q.z, W[(k+2)*HID + lane], acc);
        acc = fmaf(q.w, W[(k+3)*HID + lane], acc);
    }
    h[(size_t)n*HID + lane] = fmaxf(acc, 0.f);
}

// ---------------- batchnorm stats (two-stage, deterministic) ----------------
__global__ __launch_bounds__(256) void k_stats_partial(
    const float* __restrict__ h, float* __restrict__ partials) {
    int b = blockIdx.x;
    int tid = threadIdx.x;
    int c = tid & 63, r0 = tid >> 6;
    float s = 0.f, s2 = 0.f;
    int row0 = b*64;
#pragma unroll
    for (int k = 0; k < 16; ++k) {
        float v = h[(size_t)(row0 + r0 + 4*k)*HID + c];
        s += v; s2 += v*v;
    }
    __shared__ float ls[256], l2[256];
    ls[tid] = s; l2[tid] = s2;
    __syncthreads();
    if (tid < 64) {
        s  = ls[tid] + ls[tid+64] + ls[tid+128] + ls[tid+192];
        s2 = l2[tid] + l2[tid+64] + l2[tid+128] + l2[tid+192];
        partials[b*128 + tid]      = s;
        partials[b*128 + 64 + tid] = s2;
    }
}

__global__ __launch_bounds__(64) void k_stats_final(
    const float* __restrict__ partials, const float* __restrict__ gam,
    const float* __restrict__ bet, float* __restrict__ stats) {
    int c = threadIdx.x;
    float s = 0.f, s2 = 0.f;
    for (int b = 0; b < NN/64; ++b) {
        s  += partials[b*128 + c];
        s2 += partials[b*128 + 64 + c];
    }
    float mu  = s / (float)NN;
    float var = s2 / (float)NN - mu*mu;
    float rs  = rsqrtf(var + 1e-5f);
    float sc  = rs * gam[c];
    stats[c]      = sc;
    stats[64 + c] = bet[c] - mu*sc;
}

// ------- GINE: 8 dsts/wave, SCALAR edge-strip loads from original layout -----
__global__ __launch_bounds__(256) void k_gine(
    const float* __restrict__ h, const float* __restrict__ stats,
    const float* __restrict__ ea,
    const float* __restrict__ We, const float* __restrict__ be,
    const float* __restrict__ W1, const float* __restrict__ b1,
    const float* __restrict__ W2, const float* __restrict__ b2,
    float* __restrict__ hout) {
    int b = blockIdx.x;
    int g = b & (G-1), q = b >> 7;         // 4 quarters
    int tid = threadIdx.x, w = tid >> 6, lane = tid & 63;
    int j0 = min(q*32 + w*8, R - 8);       // clamp: overlap waves write identical values
    __shared__ float hs[R][64];
    __shared__ float t1s[4][68];
    size_t hbase = (size_t)g*R*HID;
    float scv = stats[lane], shv = stats[64 + lane];
    for (int idx = tid; idx < R*HID; idx += 256)
        hs[idx>>6][lane] = fmaf(h[hbase + idx], scv, shv);
    float w0=We[lane], w1v=We[64+lane], w2v=We[128+lane],
          w3v=We[192+lane], w4v=We[256+lane], bec=be[lane];
    __syncthreads();

    float acc[8] = {0.f,0.f,0.f,0.f,0.f,0.f,0.f,0.f};
    int sbase = __builtin_amdgcn_readfirstlane((g*R*R + j0)*EDIM);
    for (int i = 0; i < R; ++i) {
        float hv = hs[i][lane];
        const float* sp = ea + sbase + i*(R*EDIM);   // uniform -> scalar loads
#pragma unroll
        for (int j = 0; j < 8; ++j) {
            float ew = bec;
            ew = fmaf(sp[j*5+0], w0,  ew);
            ew = fmaf(sp[j*5+1], w1v, ew);
            ew = fmaf(sp[j*5+2], w2v, ew);
            ew = fmaf(sp[j*5+3], w3v, ew);
            ew = fmaf(sp[j*5+4], w4v, ew);
            acc[j] += fmaxf(hv + ew, 0.f);
        }
    }
#pragma unroll
    for (int j = 0; j < 8; ++j) {
        int jd = j0 + j;
        float h1 = hs[jd][lane] + acc[j];
        t1s[w][lane] = h1;                 // same-wave in-order LDS
        float a1 = b1[lane];
#pragma unroll
        for (int k = 0; k < HID; k += 4) {
            float4 tq = *(const float4*)&t1s[w][k];
            a1 = fmaf(tq.x, W1[(k  )*HID + lane], a1);
            a1 = fmaf(tq.y, W1[(k+1)*HID + lane], a1);
            a1 = fmaf(tq.z, W1[(k+2)*HID + lane], a1);
            a1 = fmaf(tq.w, W1[(k+3)*HID + lane], a1);
        }
        t1s[w][lane] = fmaxf(a1, 0.f);
        float a2 = b2[lane];
#pragma unroll
        for (int k = 0; k < HID; k += 4) {
            float4 tq = *(const float4*)&t1s[w][k];
            a2 = fmaf(tq.x, W2[(k  )*HID + lane], a2);
            a2 = fmaf(tq.y, W2[(k+1)*HID + lane], a2);
            a2 = fmaf(tq.z, W2[(k+2)*HID + lane], a2);
            a2 = fmaf(tq.w, W2[(k+3)*HID + lane], a2);
        }
        hout[hbase + (size_t)jd*HID + lane] = fmaxf(a2, 0.f);
    }
}

// ---------------- GAT: xl/xr projections + att-dot precompute ----------------
__global__ __launch_bounds__(256) void k_xlxr(
    const float* __restrict__ h,
    const float* __restrict__ Wl, const float* __restrict__ bl,
    const float* __restrict__ Wr, const float* __restrict__ br,
    const float* __restrict__ att,
    float* __restrict__ xl, float* __restrict__ xr,
    float* __restrict__ axl, float* __restrict__ axr) {
    int w = threadIdx.x >> 6, lane = threadIdx.x & 63;
    int n = blockIdx.x*4 + w;
    __shared__ float hr[4][68];
    hr[w][lane] = h[(size_t)n*HID + lane];
    float aL = bl[lane], aR = br[lane];
#pragma unroll
    for (int k = 0; k < HID; k += 4) {
        float4 q = *(const float4*)&hr[w][k];
        aL = fmaf(q.x, Wl[(k  )*HID + lane], aL);
        aR = fmaf(q.x, Wr[(k  )*HID + lane], aR);
        aL = fmaf(q.y, Wl[(k+1)*HID + lane], aL);
        aR = fmaf(q.y, Wr[(k+1)*HID + lane], aR);
        aL = fmaf(q.z, Wl[(k+2)*HID + lane], aL);
        aR = fmaf(q.z, Wr[(k+2)*HID + lane], aR);
        aL = fmaf(q.w, Wl[(k+3)*HID + lane], aL);
        aR = fmaf(q.w, Wr[(k+3)*HID + lane], aR);
    }
    xl[(size_t)n*HID + lane] = aL;
    xr[(size_t)n*HID + lane] = aR;
    float at = att[lane];
    float pL = waveReduceSum(aL * at);
    float pR = waveReduceSum(aR * at);
    if (lane == 0) { axl[n] = pL; axr[n] = pR; }
}

// ------- GAT: r5 skeleton + scalar wepack/xr loads, b64 xls reads ------------
__global__ __launch_bounds__(256) void k_gat(
    const float* __restrict__ xl, const float* __restrict__ xr,
    const float* __restrict__ axlg, const float* __restrict__ axrg,
    const float* __restrict__ eat, const float* __restrict__ wepack,
    const float* __restrict__ wasg, const float* __restrict__ bias,
    float* __restrict__ hout) {
    int b = blockIdx.x;
    int g = b & (G-1), chunk = b >> 7;     // 8 chunks x 15 dsts
    int j0 = chunk*15, jcnt = min(15, R - j0);
    int tid = threadIdx.x, w = tid >> 6, lane = tid & 63;
    __shared__ float xls[R][66];           // stride 66: 8B-aligned rows, 2-way banks
    __shared__ float ps[4][120];
    size_t hbase = (size_t)g*R*HID;
    for (int idx = tid; idx < R*HID; idx += 256)
        xls[idx>>6][idx&63] = xl[hbase + idx];
    float biasv = bias[lane];
    float wasv0 = wasg[0], wasv1 = wasg[1], wasv2 = wasg[2],
          wasv3 = wasg[3], wasv4 = wasg[4];
    bool vB = lane < (R - 64);
    int rb = vB ? (64 + lane) : lane;      // clamped B-row
    float axA = axlg[g*R + lane];
    float axB = axlg[g*R + rb];
    __syncthreads();

    for (int jj = w; jj < jcnt; jj += 4) {
        int j = j0 + jj;
        const float* colp = eat + (size_t)(g*R + j)*R*EDIM;
        float eA[5], eB[5];
#pragma unroll
        for (int e = 0; e < 5; ++e) {
            eA[e] = colp[lane*EDIM + e];
            eB[e] = colp[rb*EDIM + e];
        }
        const float* xrp = xr + hbase + (size_t)j*HID;   // uniform -> scalar
        float axrj = axrg[g*R + j];                      // uniform
        float accA = 0.f, accB = 0.f;
#pragma unroll 4
        for (int c = 0; c < HID; c += 2) {
            float2 xA2 = *(const float2*)&xls[lane][c];
            float2 xB2 = *(const float2*)&xls[rb][c];
            {
                const float* wp = wepack + c*8;          // uniform -> scalar
                float u = xrp[c];
                float zA = xA2.x + u;
                zA = fmaf(eA[0],wp[0],zA); zA = fmaf(eA[1],wp[1],zA);
                zA = fmaf(eA[2],wp[2],zA); zA = fmaf(eA[3],wp[3],zA);
                zA = fmaf(eA[4],wp[4],zA);
                accA = fmaf(__builtin_fabsf(zA), wp[5], accA);
                float zB = xB2.x + u;
                zB = fmaf(eB[0],wp[0],zB); zB = fmaf(eB[1],wp[1],zB);
                zB = fmaf(eB[2],wp[2],zB); zB = fmaf(eB[3],wp[3],zB);
                zB = fmaf(eB[4],wp[4],zB);
                accB = fmaf(__builtin_fabsf(zB), wp[5], accB);
            }
            {
                const float* wp = wepack + (c+1)*8;
                float u = xrp[c+1];
                float zA = xA2.y + u;
                zA = fmaf(eA[0],wp[0],zA); zA = fmaf(eA[1],wp[1],zA);
                zA = fmaf(eA[2],wp[2],zA); zA = fmaf(eA[3],wp[3],zA);
                zA = fmaf(eA[4],wp[4],zA);
                accA = fmaf(__builtin_fabsf(zA), wp[5], accA);
                float zB = xB2.y + u;
                zB = fmaf(eB[0],wp[0],zB); zB = fmaf(eB[1],wp[1],zB);
                zB = fmaf(eB[2],wp[2],zB); zB = fmaf(eB[3],wp[3],zB);
                zB = fmaf(eB[4],wp[4],zB);
                accB = fmaf(__builtin_fabsf(zB), wp[5], accB);
            }
        }
        // linear part: L = axl + axr + ea . (We@att)
        float LA = axA + axrj, LB = axB + axrj;
        LA = fmaf(eA[0],wasv0,LA); LA = fmaf(eA[1],wasv1,LA);
        LA = fmaf(eA[2],wasv2,LA); LA = fmaf(eA[3],wasv3,LA);
        LA = fmaf(eA[4],wasv4,LA);
        LB = fmaf(eB[0],wasv0,LB); LB = fmaf(eB[1],wasv1,LB);
        LB = fmaf(eB[2],wasv2,LB); LB = fmaf(eB[3],wasv3,LB);
        LB = fmaf(eB[4],wasv4,LB);
        // lrelu(z,0.2) = 0.6z + 0.4|z| => score = 0.6*L + 0.4*acc
        float sA = fmaf(0.4f, accA, 0.6f*LA);
        float sB = vB ? fmaf(0.4f, accB, 0.6f*LB) : -1e30f;
        float m = fmaxf(sA, sB);
#pragma unroll
        for (int msk = 32; msk >= 1; msk >>= 1) m = fmaxf(m, __shfl_xor(m, msk, 64));
        float eAx = __expf(sA - m);
        float eBx = vB ? __expf(sB - m) : 0.f;
        float s = eAx + eBx;
#pragma unroll
        for (int msk = 32; msk >= 1; msk >>= 1) s += __shfl_xor(s, msk, 64);
        float inv = 1.f / (s + 1e-16f);
        ps[w][lane] = eAx * inv;
        if (vB) ps[w][64 + lane] = eBx * inv;
        // same-wave produce->consume
        float o = 0.f;
#pragma unroll 4
        for (int i = 0; i < R; i += 4) {
            float4 p4 = *(const float4*)&ps[w][i];
            o = fmaf(p4.x, xls[i  ][lane], o);
            o = fmaf(p4.y, xls[i+1][lane], o);
            o = fmaf(p4.z, xls[i+2][lane], o);
            o = fmaf(p4.w, xls[i+3][lane], o);
        }
        hout[hbase + (size_t)j*HID + lane] = fmaxf(o + biasv, 0.f);
    }
}

// ---------------- pooling ----------------
__global__ __launch_bounds__(256) void k_pool_score(
    const float* __restrict__ h, const float* __restrict__ W1,
    const float* __restrict__ b1, const float* __restrict__ w2,
    float* __restrict__ scores) {
    int w = threadIdx.x >> 6, lane = threadIdx.x & 63;
    int n = blockIdx.x*4 + w;
    __shared__ float hr[4][68];
    hr[w][lane] = h[(size_t)n*HID + lane];
    float acc = b1[lane];
#pragma unroll
    for (int k = 0; k < HID; k += 4) {
        float4 q = *(const float4*)&hr[w][k];
        acc = fmaf(q.x, W1[(k  )*HID + lane], acc);
        acc = fmaf(q.y, W1[(k+1)*HID + lane], acc);
        acc = fmaf(q.z, W1[(k+2)*HID + lane], acc);
        acc = fmaf(q.w, W1[(k+3)*HID + lane], acc);
    }
    float p = tanhf(acc) * w2[lane];
    p = waveReduceSum(p);
    if (lane == 0) scores[n] = p;
}

__global__ __launch_bounds__(1024) void k_pool_reduce(
    const float* __restrict__ scores, float* __restrict__ ms) {
    __shared__ float red[1024];
    int tid = threadIdx.x;
    float m = -1e30f;
    for (int i = tid; i < NN; i += 1024) m = fmaxf(m, scores[i]);
    red[tid] = m;
    __syncthreads();
    for (int s = 512; s > 0; s >>= 1) {
        if (tid < s) red[tid] = fmaxf(red[tid], red[tid+s]);
        __syncthreads();
    }
    float mx = red[0];
    __syncthreads();
    float sum = 0.f;
    for (int i = tid; i < NN; i += 1024) sum += __expf(scores[i] - mx);
    red[tid] = sum;
    __syncthreads();
    for (int s = 512; s > 0; s >>= 1) {
        if (tid < s) red[tid] += red[tid+s];
        __syncthreads();
    }
    if (tid == 0) { ms[0] = mx; ms[1] = red[0]; }
}

__global__ __launch_bounds__(64) void k_pool_final(
    const float* __restrict__ h, const float* __restrict__ scores,
    const float* __restrict__ ms,
    const float* __restrict__ lin1W, const float* __restrict__ lin1b,
    const float* __restrict__ lin2W, const float* __restrict__ lin2b,
    float* __restrict__ out) {
    int g = blockIdx.x, c = threadIdx.x;
    float mx = ms[0], inv = 1.f / ms[1];
    float pc = 0.f;
    int nb = g*R;
    for (int r = 0; r < R; ++r) {
        float wv = __expf(scores[nb + r] - mx) * inv;
        pc = fmaf(h[(size_t)(nb + r)*HID + c], wv, pc);
    }
    __shared__ float pl[HID];
    __shared__ float t[INCH];
    pl[c] = pc;
    __syncthreads();
    for (int k = c; k < INCH; k += 64) {
        float acc = lin1b[k];
#pragma unroll 8
        for (int q = 0; q < HID; ++q) acc = fmaf(pl[q], lin1W[q*INCH + k], acc);
        t[k] = fmaxf(acc, 0.f);
    }
    __syncthreads();
    if (c < 2) {
        float o = lin2b[c];
        for (int k = 0; k < INCH; ++k) o = fmaf(t[k], lin2W[k*2 + c], o);
        out[g*2 + c] = o;
    }
}

extern "C" void kernel_launch(void* const* d_in, const int* in_sizes, int n_in,
                              void* d_out, int out_size, void* d_ws, size_t ws_size,
                              hipStream_t stream) {
    (void)in_sizes; (void)n_in; (void)out_size; (void)ws_size;
    const float* x        = (const float*)d_in[0];
    const float* edge_attr= (const float*)d_in[1];
    const float* emb      = (const float*)d_in[2];
    const float* enc_W    = (const float*)d_in[3];
    const float* enc_b    = (const float*)d_in[4];
    const float* bn_g     = (const float*)d_in[5];
    const float* bn_b     = (const float*)d_in[6];
    const float* gine_We  = (const float*)d_in[7];
    const float* gine_be  = (const float*)d_in[8];
    const float* gine_W1  = (const float*)d_in[9];
    const float* gine_b1  = (const float*)d_in[10];
    const float* gine_W2  = (const float*)d_in[11];
    const float* gine_b2  = (const float*)d_in[12];
    const float* gat_Wl   = (const float*)d_in[13];
    const float* gat_bl   = (const float*)d_in[14];
    const float* gat_Wr   = (const float*)d_in[15];
    const float* gat_br   = (const float*)d_in[16];
    const float* gat_att  = (const float*)d_in[17];
    const float* gat_We   = (const float*)d_in[18];
    const float* gat_bias = (const float*)d_in[19];
    const float* pool_W1  = (const float*)d_in[20];
    const float* pool_b1  = (const float*)d_in[21];
    const float* pool_w2  = (const float*)d_in[22];
    const float* lin1_W   = (const float*)d_in[23];
    const float* lin1_b   = (const float*)d_in[24];
    const float* lin2_W   = (const float*)d_in[25];
    const float* lin2_b   = (const float*)d_in[26];
    const int*   group_ids= (const int*)d_in[29];
    float* out = (float*)d_out;

    float* w = (float*)d_ws;
    float* eat      = w;                            // R2*G*EDIM
    float* hA       = eat + (size_t)R2*G*EDIM;      // NN*HID
    float* hB       = hA + (size_t)NN*HID;
    float* xlb      = hB + (size_t)NN*HID;
    float* xrb      = xlb + (size_t)NN*HID;
    float* axl      = xrb + (size_t)NN*HID;         // NN
    float* axr      = axl + NN;                     // NN
    float* scores   = axr + NN;                     // NN
    float* partials = scores + NN;                  // 232*128
    float* stats    = partials + (NN/64)*128;       // 128
    float* pms      = stats + 128;                  // 2
    float* wepack   = pms + 2;                      // 2*64*8
    float* was2     = wepack + 2*HID*8;             // 2*8

    k_etr<<<G*16, 256, 0, stream>>>(edge_attr, eat);
    k_prep<<<2, 64, 0, stream>>>(gat_We, gat_att, wepack, was2);
    k_encode<<<NN/4, 256, 0, stream>>>(x, emb, group_ids, enc_W, enc_b, hA);
    k_stats_partial<<<NN/64, 256, 0, stream>>>(hA, partials);
    k_stats_final<<<1, 64, 0, stream>>>(partials, bn_g, bn_b, stats);
    k_gine<<<G*4, 256, 0, stream>>>(hA, stats, edge_attr, gine_We, gine_be,
                                    gine_W1, gine_b1, gine_W2, gine_b2, hB);
    // GAT layer 0: hB -> hA
    k_xlxr<<<NN/4, 256, 0, stream>>>(hB, gat_Wl, gat_bl, gat_Wr, gat_br,
                                     gat_att, xlb, xrb, axl, axr);
    k_gat<<<G*8, 256, 0, stream>>>(xlb, xrb, axl, axr, eat, wepack,
                                   was2, gat_bias, hA);
    // GAT layer 1: hA -> hB
    k_xlxr<<<NN/4, 256, 0, stream>>>(hA, gat_Wl + HID*HID, gat_bl + HID,
                                     gat_Wr + HID*HID, gat_br + HID,
                                     gat_att + HID, xlb, xrb, axl, axr);
    k_gat<<<G*8, 256, 0, stream>>>(xlb, xrb, axl, axr, eat, wepack + HID*8,
                                   was2 + 8, gat_bias + HID, hB);
    // pooling + head
    k_pool_score<<<NN/4, 256, 0, stream>>>(hB, pool_W1, pool_b1, pool_w2, scores);
    k_pool_reduce<<<1, 1024, 0, stream>>>(scores, pms);
    k_pool_final<<<G, 64, 0, stream>>>(hB, scores, pms, lin1_W, lin1_b,
                                       lin2_W, lin2_b, out);
}